// Round 12
// baseline (328.161 us; speedup 1.0000x reference)
//
#include <hip/hip_runtime.h>
#include <hip/hip_bf16.h>

// Problem constants (reference): IN_DIM = HID = 64, K = 3, NCLS = 10.
// All compute fp32. Output fp32 (B*10).
//
// CSR build (no global atomics; counting sort by dst).  R11 post-mortem:
// the edge arrays were re-read P=16 times by hist+fill (~300 MB).  Now:
//   - histograms: PART_H=25088 nodes (u16-packed LDS counters, 50 KB),
//     P_H=4 -> edge re-reads 153 -> 38 MB.  One launch covers src+dst.
//   - fill: u8-packed LDS cursors (12.5 KB) at P_F=8 (XCD-pinned csr
//     writes, verified R3->R6), absolute pos = rowptr[d] (L2-hot) + u8 off.
//
// GEMM: LDS-tiled 128-node tile (R11: off the top-5).
// Gather: at its structural fabric floor (138 MB fetch ~ the 158 MB
// random-graph minimum; 3.3 TB/s) — left unchanged.

#define PART_H 25088
#define HALF_H (PART_H / 2)
#define PART_F 12544
#define QUART_F (PART_F / 4)
#define MCH  64

// ----------------------- histogram (u16-packed LDS), one launch, both arrays
// blockIdx.x = a*(P_H*MCH) + m*P_H + p;  a: 0=dst->hd, 1=src->hs
__global__ void k_hist1(const int* __restrict__ esrc, const int* __restrict__ edst,
                        unsigned char* __restrict__ hd, unsigned char* __restrict__ hs,
                        int N, int E, int PH) {
  __shared__ unsigned int lc[HALF_H];
  const int b = blockIdx.x;
  const int half = PH * MCH;
  const int a = b / half;
  const int r = b % half;
  const int p = r % PH;
  const int m = r / PH;
  const int* __restrict__ arr = a ? esrc : edst;
  unsigned char* __restrict__ outp = a ? hs : hd;
  const int base = p * PART_H;
  const int lim = min(PART_H, N - base);
  for (int i = threadIdx.x; i < HALF_H; i += blockDim.x) lc[i] = 0u;
  __syncthreads();
  const long long cb = (long long)m * E / MCH;
  const long long ce = (long long)(m + 1) * E / MCH;
  const long long a0 = min((cb + 3) & ~3LL, ce);
  const long long nv = (ce - a0) >> 2;
  for (long long e = cb + threadIdx.x; e < a0; e += blockDim.x) {
    int d = arr[e] - base;
    if ((unsigned)d < (unsigned)lim) atomicAdd(&lc[d >> 1], 1u << ((d & 1) * 16));
  }
  const int4* __restrict__ a4p = (const int4*)(arr + a0);
  for (long long i = threadIdx.x; i < nv; i += blockDim.x) {
    int4 v4 = a4p[i];
    int d;
    d = v4.x - base; if ((unsigned)d < (unsigned)lim) atomicAdd(&lc[d >> 1], 1u << ((d & 1) * 16));
    d = v4.y - base; if ((unsigned)d < (unsigned)lim) atomicAdd(&lc[d >> 1], 1u << ((d & 1) * 16));
    d = v4.z - base; if ((unsigned)d < (unsigned)lim) atomicAdd(&lc[d >> 1], 1u << ((d & 1) * 16));
    d = v4.w - base; if ((unsigned)d < (unsigned)lim) atomicAdd(&lc[d >> 1], 1u << ((d & 1) * 16));
  }
  for (long long e = a0 + (nv << 2) + threadIdx.x; e < ce; e += blockDim.x) {
    int d = arr[e] - base;
    if ((unsigned)d < (unsigned)lim) atomicAdd(&lc[d >> 1], 1u << ((d & 1) * 16));
  }
  __syncthreads();
  unsigned char* slice = outp + ((size_t)p * MCH + m) * PART_H;
  for (int i = threadIdx.x; i < lim; i += blockDim.x)
    slice[i] = (unsigned char)((lc[i >> 1] >> ((i & 1) * 16)) & 0xffffu);
}

// ---------------- counts -> in-row prefix offsets (u8, in place) + degs/norms
__global__ void k_off(unsigned char* __restrict__ hd, const unsigned char* __restrict__ hs,
                      int* __restrict__ deg_d, float* __restrict__ norm_s,
                      float* __restrict__ norm_d, int N) {
  int v = blockIdx.x * blockDim.x + threadIdx.x;
  if (v >= N) return;
  size_t base = (size_t)(v / PART_H) * MCH * PART_H + (v % PART_H);
  int run = 0;
#pragma unroll
  for (int m = 0; m < MCH; ++m) {
    int t = hd[base + (size_t)m * PART_H];
    hd[base + (size_t)m * PART_H] = (unsigned char)run;
    run += t;
  }
  int s = 0;
#pragma unroll
  for (int m = 0; m < MCH; ++m) s += hs[base + (size_t)m * PART_H];
  deg_d[v] = run;
  norm_d[v] = rsqrtf((float)max(run, 1));
  norm_s[v] = rsqrtf((float)max(s, 1));
}

// ------------------------------------------------------------ CSR scan
__global__ void k_scan1(const int* __restrict__ deg, int* __restrict__ rowptr,
                        int* __restrict__ bsum, int N) {
  __shared__ int sums[256];
  const int t = threadIdx.x;
  const int base = blockIdx.x * 2048 + t * 8;
  int loc[8];
  int tot = 0;
#pragma unroll
  for (int j = 0; j < 8; ++j) {
    int idx = base + j;
    loc[j] = tot;
    tot += (idx < N) ? deg[idx] : 0;
  }
  sums[t] = tot;
  __syncthreads();
  for (int off = 1; off < 256; off <<= 1) {
    int x = (t >= off) ? sums[t - off] : 0;
    __syncthreads();
    sums[t] += x;
    __syncthreads();
  }
  int excl = (t == 0) ? 0 : sums[t - 1];
#pragma unroll
  for (int j = 0; j < 8; ++j) {
    int idx = base + j;
    if (idx < N) rowptr[idx] = excl + loc[j];
  }
  if (t == 255) bsum[blockIdx.x] = sums[255];
}

__global__ void k_scan2(int* __restrict__ bsum, int nb) {
  int lane = threadIdx.x;
  int v = (lane < nb) ? bsum[lane] : 0;
  int inc = v;
#pragma unroll
  for (int off = 1; off < 64; off <<= 1) {
    int o = __shfl_up(inc, off, 64);
    if (lane >= off) inc += o;
  }
  if (lane < nb) bsum[lane] = inc - v;
}

__global__ void k_scan3(int* __restrict__ rowptr, const int* __restrict__ bsum, int N) {
  int v = blockIdx.x * blockDim.x + threadIdx.x;
  if (v < N) rowptr[v] += bsum[v >> 11];
}

// --------------------------- fill (u8-packed LDS cursors, no global atomics)
// blockIdx.x = m*P_F + p  (XCD pin: partition p's csr writes -> XCD p%8 L2).
// LDS cursor = per-node u8 (4/word); absolute = rowptr[d] (L2-hot) + u8.
__global__ void k_fill2(const int* __restrict__ esrc, const int* __restrict__ edst,
                        const unsigned char* __restrict__ hd, const int* __restrict__ rowptr,
                        int* __restrict__ csr, int N, int E, int PF) {
  __shared__ unsigned int cur4[QUART_F];
  const int b = blockIdx.x;
  const int p = b % PF;
  const int m = b / PF;
  const int base = p * PART_F;
  const int lim = min(PART_F, N - base);
  // hd slice for (partition p, chunk m): contiguous PART_F bytes inside the
  // PART_H-partition layout.
  const unsigned char* slice = hd + ((size_t)(p >> 1) * MCH + m) * PART_H
                                  + (size_t)(p & 1) * PART_F;
  const unsigned int* slice4 = (const unsigned int*)slice;
  for (int i = threadIdx.x; i < QUART_F; i += blockDim.x) cur4[i] = slice4[i];
  __syncthreads();
  const int* __restrict__ rp = rowptr + base;
  const long long cb = (long long)m * E / MCH;
  const long long ce = (long long)(m + 1) * E / MCH;
  const long long a0 = min((cb + 3) & ~3LL, ce);
  const long long nv = (ce - a0) >> 2;
  for (long long e = cb + threadIdx.x; e < a0; e += blockDim.x) {
    int d = edst[e] - base;
    if ((unsigned)d < (unsigned)lim) {
      unsigned int old = atomicAdd(&cur4[d >> 2], 1u << ((d & 3) * 8));
      int off = (old >> ((d & 3) * 8)) & 0xff;
      csr[rp[d] + off] = esrc[e];
    }
  }
  const int4* __restrict__ d4p = (const int4*)(edst + a0);
  const int4* __restrict__ s4p = (const int4*)(esrc + a0);
  for (long long i = threadIdx.x; i < nv; i += blockDim.x) {
    int4 d4 = d4p[i];
    int4 s4 = s4p[i];
    int d;
    d = d4.x - base;
    if ((unsigned)d < (unsigned)lim) {
      unsigned int old = atomicAdd(&cur4[d >> 2], 1u << ((d & 3) * 8));
      csr[rp[d] + ((old >> ((d & 3) * 8)) & 0xff)] = s4.x;
    }
    d = d4.y - base;
    if ((unsigned)d < (unsigned)lim) {
      unsigned int old = atomicAdd(&cur4[d >> 2], 1u << ((d & 3) * 8));
      csr[rp[d] + ((old >> ((d & 3) * 8)) & 0xff)] = s4.y;
    }
    d = d4.z - base;
    if ((unsigned)d < (unsigned)lim) {
      unsigned int old = atomicAdd(&cur4[d >> 2], 1u << ((d & 3) * 8));
      csr[rp[d] + ((old >> ((d & 3) * 8)) & 0xff)] = s4.z;
    }
    d = d4.w - base;
    if ((unsigned)d < (unsigned)lim) {
      unsigned int old = atomicAdd(&cur4[d >> 2], 1u << ((d & 3) * 8));
      csr[rp[d] + ((old >> ((d & 3) * 8)) & 0xff)] = s4.w;
    }
  }
  for (long long e = a0 + (nv << 2) + threadIdx.x; e < ce; e += blockDim.x) {
    int d = edst[e] - base;
    if ((unsigned)d < (unsigned)lim) {
      unsigned int old = atomicAdd(&cur4[d >> 2], 1u << ((d & 3) * 8));
      csr[rp[d] + ((old >> ((d & 3) * 8)) & 0xff)] = esrc[e];
    }
  }
}

// ------------------------------------------------- (N,64) @ (64,64) GEMM
// LDS-tiled: 128-node tile per 256-thread block, A column-major (stride 136).
__global__ void __launch_bounds__(256) k_gemm64(
    const float* __restrict__ in, const float* __restrict__ norm,
    const float* __restrict__ W, float* __restrict__ out, int N) {
  __shared__ float Wl[4096];
  __shared__ float Ac[64 * 136];
  const int t = threadIdx.x;
  const int ch = (t & 7) * 8;
  const int nb = (t >> 3) * 4;
  for (int i = t; i < 1024; i += 256)
    ((float4*)Wl)[i] = ((const float4*)W)[i];

  const int NT = (N + 127) >> 7;
  for (int tile = blockIdx.x; tile < NT; tile += gridDim.x) {
    const int vbase = tile << 7;
    __syncthreads();
    for (int i = t; i < 2048; i += 256) {
      const int r = i >> 4;
      const int c = (i & 15) * 4;
      const int v = vbase + r;
      float4 val = make_float4(0.f, 0.f, 0.f, 0.f);
      if (v < N) val = *(const float4*)(in + (size_t)v * 64 + c);
      Ac[(c + 0) * 136 + r] = val.x;
      Ac[(c + 1) * 136 + r] = val.y;
      Ac[(c + 2) * 136 + r] = val.z;
      Ac[(c + 3) * 136 + r] = val.w;
    }
    __syncthreads();

    float acc[4][8];
#pragma unroll
    for (int j = 0; j < 4; ++j)
#pragma unroll
      for (int c = 0; c < 8; ++c) acc[j][c] = 0.f;

    for (int k = 0; k < 64; k += 4) {
#pragma unroll
      for (int kk = 0; kk < 4; ++kk) {
        const float4 aa = *(const float4*)&Ac[(k + kk) * 136 + nb];
        const float4 w0 = *(const float4*)&Wl[(k + kk) * 64 + ch];
        const float4 w1 = *(const float4*)&Wl[(k + kk) * 64 + ch + 4];
        const float an[4] = {aa.x, aa.y, aa.z, aa.w};
        const float wn[8] = {w0.x, w0.y, w0.z, w0.w, w1.x, w1.y, w1.z, w1.w};
#pragma unroll
        for (int j = 0; j < 4; ++j)
#pragma unroll
          for (int c = 0; c < 8; ++c)
            acc[j][c] = fmaf(an[j], wn[c], acc[j][c]);
      }
    }

#pragma unroll
    for (int j = 0; j < 4; ++j) {
      const int v = vbase + nb + j;
      if (v < N) {
        const float nm = norm[v];
        float4 o0, o1;
        o0.x = acc[j][0] * nm; o0.y = acc[j][1] * nm;
        o0.z = acc[j][2] * nm; o0.w = acc[j][3] * nm;
        o1.x = acc[j][4] * nm; o1.y = acc[j][5] * nm;
        o1.z = acc[j][6] * nm; o1.w = acc[j][7] * nm;
        *(float4*)(out + (size_t)v * 64 + ch)     = o0;
        *(float4*)(out + (size_t)v * 64 + ch + 4) = o1;
      }
    }
  }
}

// ---------------------------------------- CSR gather + fused epilogue
__global__ void k_gather(const float* __restrict__ m, const int* __restrict__ rowptr,
                         const int* __restrict__ deg, const float* __restrict__ norm_d,
                         const float* __restrict__ bias, const int* __restrict__ csr,
                         float* __restrict__ h, float* __restrict__ key, int N) {
  const int w = blockIdx.x * (blockDim.x >> 6) + (threadIdx.x >> 6);
  if (w >= N) return;
  const int lane = threadIdx.x & 63;
  const int quad = lane & 15;
  const int grp = lane >> 4;
  const int start = rowptr[w];
  const int cnt = deg[w];
  float4 acc0 = make_float4(0.f, 0.f, 0.f, 0.f);
  float4 acc1 = make_float4(0.f, 0.f, 0.f, 0.f);
  int i = grp;
  for (; i + 4 < cnt; i += 8) {
    int s0 = csr[start + i];
    int s1 = csr[start + i + 4];
    const float4 v0 = *(const float4*)(m + (size_t)s0 * 64 + quad * 4);
    const float4 v1 = *(const float4*)(m + (size_t)s1 * 64 + quad * 4);
    acc0.x += v0.x; acc0.y += v0.y; acc0.z += v0.z; acc0.w += v0.w;
    acc1.x += v1.x; acc1.y += v1.y; acc1.z += v1.z; acc1.w += v1.w;
  }
  if (i < cnt) {
    int s0 = csr[start + i];
    const float4 v0 = *(const float4*)(m + (size_t)s0 * 64 + quad * 4);
    acc0.x += v0.x; acc0.y += v0.y; acc0.z += v0.z; acc0.w += v0.w;
  }
  acc0.x += acc1.x; acc0.y += acc1.y; acc0.z += acc1.z; acc0.w += acc1.w;
#pragma unroll
  for (int off = 16; off <= 32; off <<= 1) {
    acc0.x += __shfl_xor(acc0.x, off, 64);
    acc0.y += __shfl_xor(acc0.y, off, 64);
    acc0.z += __shfl_xor(acc0.z, off, 64);
    acc0.w += __shfl_xor(acc0.w, off, 64);
  }
  const float nd = norm_d[w];
  const float4 bq = *(const float4*)(bias + quad * 4);
  float4 o;
  o.x = fmaxf(fmaf(acc0.x, nd, bq.x), 0.f);
  o.y = fmaxf(fmaf(acc0.y, nd, bq.y), 0.f);
  o.z = fmaxf(fmaf(acc0.z, nd, bq.z), 0.f);
  o.w = fmaxf(fmaf(acc0.w, nd, bq.w), 0.f);
  if (grp == 0) *(float4*)(h + (size_t)w * 64 + quad * 4) = o;
  if (key != nullptr) {
    float mx = fmaxf(fmaxf(o.x, o.y), fmaxf(o.z, o.w));
#pragma unroll
    for (int off = 1; off < 16; off <<= 1) mx = fmaxf(mx, __shfl_xor(mx, off, 64));
    if (lane == 0) key[w] = mx;
  }
}

// ------------------------------------------- per-graph ranges (no atomics)
__global__ void k_bstart(const int* __restrict__ gid, int* __restrict__ gstart, int N) {
  int i = blockIdx.x * blockDim.x + threadIdx.x;
  if (i >= N) return;
  int g = gid[i];
  if (i == 0 || gid[i - 1] != g) gstart[g] = i;
}

__global__ void k_bfin(const int* __restrict__ gstart, int* __restrict__ gcnt,
                       int B, int N) {
  __shared__ int sm[512];
  const int g = threadIdx.x;
  sm[g] = (g < B) ? gstart[g] : 0x7fffffff;
  __syncthreads();
  for (int off = 1; off < 512; off <<= 1) {
    int x = (g + off < 512) ? sm[g + off] : 0x7fffffff;
    __syncthreads();
    sm[g] = min(sm[g], x);
    __syncthreads();
  }
  if (g < B) {
    int gs = gstart[g];
    int ns = (g + 1 < 512) ? min(sm[g + 1], N) : N;
    gcnt[g] = (gs < N) ? (ns - gs) : 0;
  }
}

// --------------------------------------------------- top-3 keys per graph
__global__ void k_top3(const float* __restrict__ key, const int* __restrict__ gstart,
                       const int* __restrict__ gcnt, int* __restrict__ sel, int B) {
  const int lane = threadIdx.x & 63;
  const int g = blockIdx.x * (blockDim.x >> 6) + (threadIdx.x >> 6);
  if (g >= B) return;
  const int s = gstart[g], c = gcnt[g];
  float v0 = -1.f, v1 = -1.f, v2 = -1.f;
  int i0 = 0x7fffffff, i1 = 0x7fffffff, i2 = 0x7fffffff;
  for (int i = s + lane; i < s + c; i += 64) {
    float kv = key[i];
    if (kv > v0 || (kv == v0 && i < i0)) {
      v2 = v1; i2 = i1; v1 = v0; i1 = i0; v0 = kv; i0 = i;
    } else if (kv > v1 || (kv == v1 && i < i1)) {
      v2 = v1; i2 = i1; v1 = kv; i1 = i;
    } else if (kv > v2 || (kv == v2 && i < i2)) {
      v2 = kv; i2 = i;
    }
  }
  int ptr = 0;
  for (int r = 0; r < 3; ++r) {
    float mv = (ptr == 0) ? v0 : (ptr == 1) ? v1 : (ptr == 2) ? v2 : -1.f;
    int   mi = (ptr == 0) ? i0 : (ptr == 1) ? i1 : (ptr == 2) ? i2 : 0x7fffffff;
    float bv = mv; int bi = mi;
#pragma unroll
    for (int off = 32; off; off >>= 1) {
      float ov = __shfl_xor(bv, off, 64);
      int   oi = __shfl_xor(bi, off, 64);
      if (ov > bv || (ov == bv && oi < bi)) { bv = ov; bi = oi; }
    }
    if (bi == mi && ptr < 3) ptr++;             // winner's owner pops
    if (lane == 0) sel[g * 3 + r] = (bi == 0x7fffffff) ? -1 : bi;
  }
}

// ------------------------------------- gather selected rows + bitonic sort
__global__ void k_pool(const float* __restrict__ h, const int* __restrict__ sel,
                       float* __restrict__ p, int B) {
  const int lane = threadIdx.x & 63;
  const int w = blockIdx.x * (blockDim.x >> 6) + (threadIdx.x >> 6);
  if (w >= B * 3) return;
  int node = sel[w];
  float v = 0.f;
  if (node >= 0) {
    v = h[(size_t)node * 64 + lane];
    for (int k2 = 2; k2 <= 64; k2 <<= 1) {
      for (int j = k2 >> 1; j > 0; j >>= 1) {
        float o = __shfl_xor(v, j, 64);
        bool up = ((lane & k2) == 0);
        bool lower = ((lane & j) == 0);
        v = (lower == up) ? fminf(v, o) : fmaxf(v, o);
      }
    }
  }
  p[(size_t)w * 64 + lane] = v;
}

// ---------------------------------------------------------- classifier
__global__ void k_cls(const float* __restrict__ p, const float* __restrict__ cw,
                      const float* __restrict__ cb, const float* __restrict__ Wc,
                      const float* __restrict__ bc, float* __restrict__ out, int B) {
  __shared__ float prow[192];
  const int b = blockIdx.x;
  const int lane = threadIdx.x;
  prow[lane] = p[(size_t)b * 192 + lane];
  prow[lane + 64] = p[(size_t)b * 192 + lane + 64];
  prow[lane + 128] = p[(size_t)b * 192 + lane + 128];
  __syncthreads();
  float y = cb[lane];
  for (int j = 0; j < 192; ++j) y = fmaf(prow[j], cw[lane * 192 + j], y);
  float ry = fmaxf(y, 0.f);
  for (int c = 0; c < 10; ++c) {
    float s = ry * Wc[lane * 10 + c];
#pragma unroll
    for (int off = 32; off; off >>= 1) s += __shfl_xor(s, off, 64);
    if (lane == 0) out[b * 10 + c] = s + bc[c];
  }
}

// ================================================================ launch
extern "C" void kernel_launch(void* const* d_in, const int* in_sizes, int n_in,
                              void* d_out, int out_size, void* d_ws, size_t ws_size,
                              hipStream_t stream) {
  const float* features = (const float*)d_in[0];
  const int*   esrc     = (const int*)d_in[1];
  const int*   edst     = (const int*)d_in[2];
  const int*   gid      = (const int*)d_in[3];
  const float* W1 = (const float*)d_in[5];
  const float* b1 = (const float*)d_in[6];
  const float* W2 = (const float*)d_in[7];
  const float* b2 = (const float*)d_in[8];
  const float* cw = (const float*)d_in[9];
  const float* cb = (const float*)d_in[10];
  const float* Wc = (const float*)d_in[11];
  const float* bc = (const float*)d_in[12];
  float* out = (float*)d_out;

  const int N = in_sizes[0] / 64;
  const int E = in_sizes[1];
  const int B = out_size / 10;
  const size_t N64 = (size_t)N * 64;
  const int nscan = (N + 2047) / 2048;          // <= 64 for N <= 131072
  const int PH = (N + PART_H - 1) / PART_H;     // 4 for N=100k
  const int PF = (N + PART_F - 1) / PART_F;     // 8 for N=100k -> XCD pin
  const size_t HSZ = (size_t)PH * MCH * PART_H; // u8 hist bytes (~6.4 MB)
  const int NT = (N + 127) / 128;               // gemm tiles

  // workspace carve-up (~75 MB of the 256 MB ws; fully disjoint).
  float* bufA   = (float*)d_ws;            // N*64 : m1 -> m2
  float* bufB   = bufA + N64;              // N*64 : h1 -> h2
  int*   deg_d  = (int*)(bufB + N64);      // N
  float* norm_s = (float*)(deg_d + N);     // N
  float* norm_d = norm_s + N;              // N
  float* key    = norm_d + N;              // N
  int*   rowptr = (int*)(key + N);         // N
  int*   csr    = rowptr + N;              // E
  int*   bsum   = csr + E;                 // <=64
  int*   gstart = bsum + 64;               // B
  int*   gcnt   = gstart + B;              // B
  int*   sel    = gcnt + B;                // 3B
  float* p      = (float*)(sel + 3 * B);   // 192B
  unsigned char* hd = (unsigned char*)(p + 192 * B); // HSZ u8
  unsigned char* hs = hd + HSZ;                      // HSZ u8

  const int TB = 256;

  // ---- CSR build (no global atomics)
  k_hist1<<<2 * PH * MCH, TB, 0, stream>>>(esrc, edst, hd, hs, N, E, PH);
  k_off<<<(N + TB - 1) / TB, TB, 0, stream>>>(hd, hs, deg_d, norm_s, norm_d, N);
  k_scan1<<<nscan, 256, 0, stream>>>(deg_d, rowptr, bsum, N);
  k_scan2<<<1, 64, 0, stream>>>(bsum, nscan);
  k_scan3<<<(N + TB - 1) / TB, TB, 0, stream>>>(rowptr, bsum, N);
  k_fill2<<<PF * MCH, TB, 0, stream>>>(esrc, edst, hd, rowptr, csr, N, E, PF);

  // ---- layer 1
  k_gemm64<<<NT, TB, 0, stream>>>(features, norm_s, W1, bufA, N);
  k_gather<<<(N + 3) / 4, TB, 0, stream>>>(bufA, rowptr, deg_d, norm_d, b1, csr,
                                           bufB, nullptr, N);

  // ---- layer 2 (key = row max fused)
  k_gemm64<<<NT, TB, 0, stream>>>(bufB, norm_s, W2, bufA, N);
  k_gather<<<(N + 3) / 4, TB, 0, stream>>>(bufA, rowptr, deg_d, norm_d, b2, csr,
                                           bufB, key, N);

  // ---- sort-pool (boundary detection on sorted gid; no atomics)
  hipMemsetAsync(gstart, 0x7f, (size_t)B * sizeof(int), stream);
  k_bstart<<<(N + TB - 1) / TB, TB, 0, stream>>>(gid, gstart, N);
  k_bfin<<<1, 512, 0, stream>>>(gstart, gcnt, B, N);
  k_top3<<<(B + 3) / 4, TB, 0, stream>>>(key, gstart, gcnt, sel, B);
  k_pool<<<(B * 3 + 3) / 4, TB, 0, stream>>>(bufB, sel, p, B);

  // ---- classifier
  k_cls<<<B, 64, 0, stream>>>(p, cw, cb, Wc, bc, out, B);
}

// Round 13
// 307.138 us; speedup vs baseline: 1.0684x; 1.0684x over previous
//
#include <hip/hip_runtime.h>
#include <hip/hip_bf16.h>

// Problem constants (reference): IN_DIM = HID = 64, K = 3, NCLS = 10.
// All compute fp32. Output fp32 (B*10).
//
// Pipeline (R12 consolidation):
//   k_histgemm : heterogeneous grid — hist blocks (u16-packed LDS counters,
//                PART_H=25088, PH=4) + gemm1 tile blocks (no norm; the
//                norm_s factor is applied per-source inside gather1, which
//                removes gemm1's dependency on the CSR build and lets it
//                overlap the histogram pass).
//   k_off/scan : u8 chunk offsets in place + rowptr scan.
//   k_fill2    : u8-packed LDS cursors, XCD-pinned csr writes (PART_F=12544).
//   k_gather   : fabric-floor bound (138 MB fetch @ 3.3 TB/s — structural);
//                gather1 applies norm_s per source row; gather2 fuses the
//                sorted-gid boundary detection (bstart).
//   k_tail     : per-graph block — top3 + bitonic sort-pool + classifier.

#define PART_H 25088
#define HALF_H (PART_H / 2)
#define PART_F 12544
#define QUART_F (PART_F / 4)
#define MCH  64

// ---------------- fused histogram + gemm1 (independent workloads, one grid)
// blocks [0, histBlocks): histogram a=0 dst / a=1 src
// blocks [histBlocks, gridDim): gemm tiles of layer 1 (no norm applied)
__global__ void __launch_bounds__(256) k_histgemm(
    const int* __restrict__ esrc, const int* __restrict__ edst,
    unsigned char* __restrict__ hd, unsigned char* __restrict__ hs,
    const float* __restrict__ in, const float* __restrict__ W,
    float* __restrict__ mout, int N, int E, int PH, int histBlocks) {
  __shared__ float smem[12800];   // 51.2 KB union: hist counters / Wl+Ac
  const int t = threadIdx.x;
  if (blockIdx.x < histBlocks) {
    unsigned int* lc = (unsigned int*)smem;       // HALF_H u32 = 50176 B
    const int b = blockIdx.x;
    const int half = PH * MCH;
    const int a = b / half;
    const int r = b % half;
    const int p = r % PH;
    const int m = r / PH;
    const int* __restrict__ arr = a ? esrc : edst;
    unsigned char* __restrict__ outp = a ? hs : hd;
    const int base = p * PART_H;
    const int lim = min(PART_H, N - base);
    for (int i = t; i < HALF_H; i += 256) lc[i] = 0u;
    __syncthreads();
    const long long cb = (long long)m * E / MCH;
    const long long ce = (long long)(m + 1) * E / MCH;
    const long long a0 = min((cb + 3) & ~3LL, ce);
    const long long nv = (ce - a0) >> 2;
    for (long long e = cb + t; e < a0; e += 256) {
      int d = arr[e] - base;
      if ((unsigned)d < (unsigned)lim) atomicAdd(&lc[d >> 1], 1u << ((d & 1) * 16));
    }
    const int4* __restrict__ a4p = (const int4*)(arr + a0);
    for (long long i = t; i < nv; i += 256) {
      int4 v4 = a4p[i];
      int d;
      d = v4.x - base; if ((unsigned)d < (unsigned)lim) atomicAdd(&lc[d >> 1], 1u << ((d & 1) * 16));
      d = v4.y - base; if ((unsigned)d < (unsigned)lim) atomicAdd(&lc[d >> 1], 1u << ((d & 1) * 16));
      d = v4.z - base; if ((unsigned)d < (unsigned)lim) atomicAdd(&lc[d >> 1], 1u << ((d & 1) * 16));
      d = v4.w - base; if ((unsigned)d < (unsigned)lim) atomicAdd(&lc[d >> 1], 1u << ((d & 1) * 16));
    }
    for (long long e = a0 + (nv << 2) + t; e < ce; e += 256) {
      int d = arr[e] - base;
      if ((unsigned)d < (unsigned)lim) atomicAdd(&lc[d >> 1], 1u << ((d & 1) * 16));
    }
    __syncthreads();
    unsigned char* slice = outp + ((size_t)p * MCH + m) * PART_H;
    for (int i = t; i < lim; i += 256)
      slice[i] = (unsigned char)((lc[i >> 1] >> ((i & 1) * 16)) & 0xffffu);
  } else {
    float* Wl = smem;             // 4096 floats
    float* Ac = smem + 4096;      // 64*136 = 8704 floats
    const int ch = (t & 7) * 8;
    const int nb = (t >> 3) * 4;
    for (int i = t; i < 1024; i += 256)
      ((float4*)Wl)[i] = ((const float4*)W)[i];
    const int gb = blockIdx.x - histBlocks;
    const int ng = gridDim.x - histBlocks;
    const int NT = (N + 127) >> 7;
    for (int tile = gb; tile < NT; tile += ng) {
      const int vbase = tile << 7;
      __syncthreads();
      for (int i = t; i < 2048; i += 256) {
        const int r = i >> 4;
        const int c = (i & 15) * 4;
        const int v = vbase + r;
        float4 val = make_float4(0.f, 0.f, 0.f, 0.f);
        if (v < N) val = *(const float4*)(in + (size_t)v * 64 + c);
        Ac[(c + 0) * 136 + r] = val.x;
        Ac[(c + 1) * 136 + r] = val.y;
        Ac[(c + 2) * 136 + r] = val.z;
        Ac[(c + 3) * 136 + r] = val.w;
      }
      __syncthreads();
      float acc[4][8];
#pragma unroll
      for (int j = 0; j < 4; ++j)
#pragma unroll
        for (int c = 0; c < 8; ++c) acc[j][c] = 0.f;
      for (int k = 0; k < 64; k += 4) {
#pragma unroll
        for (int kk = 0; kk < 4; ++kk) {
          const float4 aa = *(const float4*)&Ac[(k + kk) * 136 + nb];
          const float4 w0 = *(const float4*)&Wl[(k + kk) * 64 + ch];
          const float4 w1 = *(const float4*)&Wl[(k + kk) * 64 + ch + 4];
          const float an[4] = {aa.x, aa.y, aa.z, aa.w};
          const float wn[8] = {w0.x, w0.y, w0.z, w0.w, w1.x, w1.y, w1.z, w1.w};
#pragma unroll
          for (int j = 0; j < 4; ++j)
#pragma unroll
            for (int c = 0; c < 8; ++c)
              acc[j][c] = fmaf(an[j], wn[c], acc[j][c]);
        }
      }
#pragma unroll
      for (int j = 0; j < 4; ++j) {
        const int v = vbase + nb + j;
        if (v < N) {
          float4 o0, o1;
          o0.x = acc[j][0]; o0.y = acc[j][1]; o0.z = acc[j][2]; o0.w = acc[j][3];
          o1.x = acc[j][4]; o1.y = acc[j][5]; o1.z = acc[j][6]; o1.w = acc[j][7];
          *(float4*)(mout + (size_t)v * 64 + ch)     = o0;
          *(float4*)(mout + (size_t)v * 64 + ch + 4) = o1;
        }
      }
    }
  }
}

// ---------------- counts -> in-row prefix offsets (u8, in place) + degs/norms
__global__ void k_off(unsigned char* __restrict__ hd, const unsigned char* __restrict__ hs,
                      int* __restrict__ deg_d, float* __restrict__ norm_s,
                      float* __restrict__ norm_d, int N) {
  int v = blockIdx.x * blockDim.x + threadIdx.x;
  if (v >= N) return;
  size_t base = (size_t)(v / PART_H) * MCH * PART_H + (v % PART_H);
  int run = 0;
#pragma unroll
  for (int m = 0; m < MCH; ++m) {
    int t = hd[base + (size_t)m * PART_H];
    hd[base + (size_t)m * PART_H] = (unsigned char)run;
    run += t;
  }
  int s = 0;
#pragma unroll
  for (int m = 0; m < MCH; ++m) s += hs[base + (size_t)m * PART_H];
  deg_d[v] = run;
  norm_d[v] = rsqrtf((float)max(run, 1));
  norm_s[v] = rsqrtf((float)max(s, 1));
}

// ------------------------------------------------------------ CSR scan
__global__ void k_scan1(const int* __restrict__ deg, int* __restrict__ rowptr,
                        int* __restrict__ bsum, int N) {
  __shared__ int sums[256];
  const int t = threadIdx.x;
  const int base = blockIdx.x * 2048 + t * 8;
  int loc[8];
  int tot = 0;
#pragma unroll
  for (int j = 0; j < 8; ++j) {
    int idx = base + j;
    loc[j] = tot;
    tot += (idx < N) ? deg[idx] : 0;
  }
  sums[t] = tot;
  __syncthreads();
  for (int off = 1; off < 256; off <<= 1) {
    int x = (t >= off) ? sums[t - off] : 0;
    __syncthreads();
    sums[t] += x;
    __syncthreads();
  }
  int excl = (t == 0) ? 0 : sums[t - 1];
#pragma unroll
  for (int j = 0; j < 8; ++j) {
    int idx = base + j;
    if (idx < N) rowptr[idx] = excl + loc[j];
  }
  if (t == 255) bsum[blockIdx.x] = sums[255];
}

__global__ void k_scan2(int* __restrict__ bsum, int nb) {
  int lane = threadIdx.x;
  int v = (lane < nb) ? bsum[lane] : 0;
  int inc = v;
#pragma unroll
  for (int off = 1; off < 64; off <<= 1) {
    int o = __shfl_up(inc, off, 64);
    if (lane >= off) inc += o;
  }
  if (lane < nb) bsum[lane] = inc - v;
}

__global__ void k_scan3(int* __restrict__ rowptr, const int* __restrict__ bsum, int N) {
  int v = blockIdx.x * blockDim.x + threadIdx.x;
  if (v < N) rowptr[v] += bsum[v >> 11];
}

// --------------------------- fill (u8-packed LDS cursors, no global atomics)
__global__ void k_fill2(const int* __restrict__ esrc, const int* __restrict__ edst,
                        const unsigned char* __restrict__ hd, const int* __restrict__ rowptr,
                        int* __restrict__ csr, int N, int E, int PF) {
  __shared__ unsigned int cur4[QUART_F];
  const int b = blockIdx.x;
  const int p = b % PF;
  const int m = b / PF;
  const int base = p * PART_F;
  const int lim = min(PART_F, N - base);
  const unsigned char* slice = hd + ((size_t)(p >> 1) * MCH + m) * PART_H
                                  + (size_t)(p & 1) * PART_F;
  const unsigned int* slice4 = (const unsigned int*)slice;
  for (int i = threadIdx.x; i < QUART_F; i += blockDim.x) cur4[i] = slice4[i];
  __syncthreads();
  const int* __restrict__ rp = rowptr + base;
  const long long cb = (long long)m * E / MCH;
  const long long ce = (long long)(m + 1) * E / MCH;
  const long long a0 = min((cb + 3) & ~3LL, ce);
  const long long nv = (ce - a0) >> 2;
  for (long long e = cb + threadIdx.x; e < a0; e += blockDim.x) {
    int d = edst[e] - base;
    if ((unsigned)d < (unsigned)lim) {
      unsigned int old = atomicAdd(&cur4[d >> 2], 1u << ((d & 3) * 8));
      csr[rp[d] + ((old >> ((d & 3) * 8)) & 0xff)] = esrc[e];
    }
  }
  const int4* __restrict__ d4p = (const int4*)(edst + a0);
  const int4* __restrict__ s4p = (const int4*)(esrc + a0);
  for (long long i = threadIdx.x; i < nv; i += blockDim.x) {
    int4 d4 = d4p[i];
    int4 s4 = s4p[i];
    int d;
    d = d4.x - base;
    if ((unsigned)d < (unsigned)lim) {
      unsigned int old = atomicAdd(&cur4[d >> 2], 1u << ((d & 3) * 8));
      csr[rp[d] + ((old >> ((d & 3) * 8)) & 0xff)] = s4.x;
    }
    d = d4.y - base;
    if ((unsigned)d < (unsigned)lim) {
      unsigned int old = atomicAdd(&cur4[d >> 2], 1u << ((d & 3) * 8));
      csr[rp[d] + ((old >> ((d & 3) * 8)) & 0xff)] = s4.y;
    }
    d = d4.z - base;
    if ((unsigned)d < (unsigned)lim) {
      unsigned int old = atomicAdd(&cur4[d >> 2], 1u << ((d & 3) * 8));
      csr[rp[d] + ((old >> ((d & 3) * 8)) & 0xff)] = s4.z;
    }
    d = d4.w - base;
    if ((unsigned)d < (unsigned)lim) {
      unsigned int old = atomicAdd(&cur4[d >> 2], 1u << ((d & 3) * 8));
      csr[rp[d] + ((old >> ((d & 3) * 8)) & 0xff)] = s4.w;
    }
  }
  for (long long e = a0 + (nv << 2) + threadIdx.x; e < ce; e += blockDim.x) {
    int d = edst[e] - base;
    if ((unsigned)d < (unsigned)lim) {
      unsigned int old = atomicAdd(&cur4[d >> 2], 1u << ((d & 3) * 8));
      csr[rp[d] + ((old >> ((d & 3) * 8)) & 0xff)] = esrc[e];
    }
  }
}

// ------------------------------------------------- (N,64) @ (64,64) GEMM
// (layer 2 only; applies norm at store)
__global__ void __launch_bounds__(256) k_gemm64(
    const float* __restrict__ in, const float* __restrict__ norm,
    const float* __restrict__ W, float* __restrict__ out, int N) {
  __shared__ float Wl[4096];
  __shared__ float Ac[64 * 136];
  const int t = threadIdx.x;
  const int ch = (t & 7) * 8;
  const int nb = (t >> 3) * 4;
  for (int i = t; i < 1024; i += 256)
    ((float4*)Wl)[i] = ((const float4*)W)[i];
  const int NT = (N + 127) >> 7;
  for (int tile = blockIdx.x; tile < NT; tile += gridDim.x) {
    const int vbase = tile << 7;
    __syncthreads();
    for (int i = t; i < 2048; i += 256) {
      const int r = i >> 4;
      const int c = (i & 15) * 4;
      const int v = vbase + r;
      float4 val = make_float4(0.f, 0.f, 0.f, 0.f);
      if (v < N) val = *(const float4*)(in + (size_t)v * 64 + c);
      Ac[(c + 0) * 136 + r] = val.x;
      Ac[(c + 1) * 136 + r] = val.y;
      Ac[(c + 2) * 136 + r] = val.z;
      Ac[(c + 3) * 136 + r] = val.w;
    }
    __syncthreads();
    float acc[4][8];
#pragma unroll
    for (int j = 0; j < 4; ++j)
#pragma unroll
      for (int c = 0; c < 8; ++c) acc[j][c] = 0.f;
    for (int k = 0; k < 64; k += 4) {
#pragma unroll
      for (int kk = 0; kk < 4; ++kk) {
        const float4 aa = *(const float4*)&Ac[(k + kk) * 136 + nb];
        const float4 w0 = *(const float4*)&Wl[(k + kk) * 64 + ch];
        const float4 w1 = *(const float4*)&Wl[(k + kk) * 64 + ch + 4];
        const float an[4] = {aa.x, aa.y, aa.z, aa.w};
        const float wn[8] = {w0.x, w0.y, w0.z, w0.w, w1.x, w1.y, w1.z, w1.w};
#pragma unroll
        for (int j = 0; j < 4; ++j)
#pragma unroll
          for (int c = 0; c < 8; ++c)
            acc[j][c] = fmaf(an[j], wn[c], acc[j][c]);
      }
    }
#pragma unroll
    for (int j = 0; j < 4; ++j) {
      const int v = vbase + nb + j;
      if (v < N) {
        const float nm = norm[v];
        float4 o0, o1;
        o0.x = acc[j][0] * nm; o0.y = acc[j][1] * nm;
        o0.z = acc[j][2] * nm; o0.w = acc[j][3] * nm;
        o1.x = acc[j][4] * nm; o1.y = acc[j][5] * nm;
        o1.z = acc[j][6] * nm; o1.w = acc[j][7] * nm;
        *(float4*)(out + (size_t)v * 64 + ch)     = o0;
        *(float4*)(out + (size_t)v * 64 + ch + 4) = o1;
      }
    }
  }
}

// ---------------------------------------- CSR gather + fused epilogue
// nsrc != nullptr: multiply each source row by norm_s[s] (layer 1).
// gid/gstart != nullptr: fused sorted-gid boundary detection (layer 2).
__global__ void k_gather(const float* __restrict__ m, const int* __restrict__ rowptr,
                         const int* __restrict__ deg, const float* __restrict__ norm_d,
                         const float* __restrict__ bias, const int* __restrict__ csr,
                         const float* __restrict__ nsrc,
                         const int* __restrict__ gid, int* __restrict__ gstart,
                         float* __restrict__ h, float* __restrict__ key, int N) {
  const int w = blockIdx.x * (blockDim.x >> 6) + (threadIdx.x >> 6);
  if (w >= N) return;
  const int lane = threadIdx.x & 63;
  const int quad = lane & 15;
  const int grp = lane >> 4;
  if (gid != nullptr && lane == 0) {
    int g = gid[w];
    if (w == 0 || gid[w - 1] != g) gstart[g] = w;
  }
  const int start = rowptr[w];
  const int cnt = deg[w];
  float4 acc0 = make_float4(0.f, 0.f, 0.f, 0.f);
  float4 acc1 = make_float4(0.f, 0.f, 0.f, 0.f);
  int i = grp;
  if (nsrc != nullptr) {
    for (; i + 4 < cnt; i += 8) {
      int s0 = csr[start + i];
      int s1 = csr[start + i + 4];
      float n0 = nsrc[s0], n1 = nsrc[s1];
      const float4 v0 = *(const float4*)(m + (size_t)s0 * 64 + quad * 4);
      const float4 v1 = *(const float4*)(m + (size_t)s1 * 64 + quad * 4);
      acc0.x = fmaf(v0.x, n0, acc0.x); acc0.y = fmaf(v0.y, n0, acc0.y);
      acc0.z = fmaf(v0.z, n0, acc0.z); acc0.w = fmaf(v0.w, n0, acc0.w);
      acc1.x = fmaf(v1.x, n1, acc1.x); acc1.y = fmaf(v1.y, n1, acc1.y);
      acc1.z = fmaf(v1.z, n1, acc1.z); acc1.w = fmaf(v1.w, n1, acc1.w);
    }
    if (i < cnt) {
      int s0 = csr[start + i];
      float n0 = nsrc[s0];
      const float4 v0 = *(const float4*)(m + (size_t)s0 * 64 + quad * 4);
      acc0.x = fmaf(v0.x, n0, acc0.x); acc0.y = fmaf(v0.y, n0, acc0.y);
      acc0.z = fmaf(v0.z, n0, acc0.z); acc0.w = fmaf(v0.w, n0, acc0.w);
    }
  } else {
    for (; i + 4 < cnt; i += 8) {
      int s0 = csr[start + i];
      int s1 = csr[start + i + 4];
      const float4 v0 = *(const float4*)(m + (size_t)s0 * 64 + quad * 4);
      const float4 v1 = *(const float4*)(m + (size_t)s1 * 64 + quad * 4);
      acc0.x += v0.x; acc0.y += v0.y; acc0.z += v0.z; acc0.w += v0.w;
      acc1.x += v1.x; acc1.y += v1.y; acc1.z += v1.z; acc1.w += v1.w;
    }
    if (i < cnt) {
      int s0 = csr[start + i];
      const float4 v0 = *(const float4*)(m + (size_t)s0 * 64 + quad * 4);
      acc0.x += v0.x; acc0.y += v0.y; acc0.z += v0.z; acc0.w += v0.w;
    }
  }
  acc0.x += acc1.x; acc0.y += acc1.y; acc0.z += acc1.z; acc0.w += acc1.w;
#pragma unroll
  for (int off = 16; off <= 32; off <<= 1) {
    acc0.x += __shfl_xor(acc0.x, off, 64);
    acc0.y += __shfl_xor(acc0.y, off, 64);
    acc0.z += __shfl_xor(acc0.z, off, 64);
    acc0.w += __shfl_xor(acc0.w, off, 64);
  }
  const float nd = norm_d[w];
  const float4 bq = *(const float4*)(bias + quad * 4);
  float4 o;
  o.x = fmaxf(fmaf(acc0.x, nd, bq.x), 0.f);
  o.y = fmaxf(fmaf(acc0.y, nd, bq.y), 0.f);
  o.z = fmaxf(fmaf(acc0.z, nd, bq.z), 0.f);
  o.w = fmaxf(fmaf(acc0.w, nd, bq.w), 0.f);
  if (grp == 0) *(float4*)(h + (size_t)w * 64 + quad * 4) = o;
  if (key != nullptr) {
    float mx = fmaxf(fmaxf(o.x, o.y), fmaxf(o.z, o.w));
#pragma unroll
    for (int off = 1; off < 16; off <<= 1) mx = fmaxf(mx, __shfl_xor(mx, off, 64));
    if (lane == 0) key[w] = mx;
  }
}

// ------------------- gcnt via suffix-min over gstart (one 512-thread block)
__global__ void k_bfin(const int* __restrict__ gstart, int* __restrict__ gcnt,
                       int B, int N) {
  __shared__ int sm[512];
  const int g = threadIdx.x;
  sm[g] = (g < B) ? gstart[g] : 0x7fffffff;
  __syncthreads();
  for (int off = 1; off < 512; off <<= 1) {
    int x = (g + off < 512) ? sm[g + off] : 0x7fffffff;
    __syncthreads();
    sm[g] = min(sm[g], x);
    __syncthreads();
  }
  if (g < B) {
    int gs = gstart[g];
    int ns = (g + 1 < 512) ? min(sm[g + 1], N) : N;
    gcnt[g] = (gs < N) ? (ns - gs) : 0;
  }
}

// ---------------- fused tail: per-graph top3 + bitonic sort-pool + classifier
__global__ void __launch_bounds__(256) k_tail(
    const float* __restrict__ key, const int* __restrict__ gstart,
    const int* __restrict__ gcnt, const float* __restrict__ h,
    const float* __restrict__ cw, const float* __restrict__ cb,
    const float* __restrict__ Wc, const float* __restrict__ bc,
    float* __restrict__ out, int B, int N) {
  __shared__ int sel[3];
  __shared__ float prow[192];
  const int b = blockIdx.x;
  const int wid = threadIdx.x >> 6;
  const int lane = threadIdx.x & 63;

  if (wid == 0) {
    const int s = gstart[b], c = gcnt[b];
    float v0 = -1.f, v1 = -1.f, v2 = -1.f;
    int i0 = 0x7fffffff, i1 = 0x7fffffff, i2 = 0x7fffffff;
    for (int i = s + lane; i < s + c; i += 64) {
      float kv = key[i];
      if (kv > v0 || (kv == v0 && i < i0)) {
        v2 = v1; i2 = i1; v1 = v0; i1 = i0; v0 = kv; i0 = i;
      } else if (kv > v1 || (kv == v1 && i < i1)) {
        v2 = v1; i2 = i1; v1 = kv; i1 = i;
      } else if (kv > v2 || (kv == v2 && i < i2)) {
        v2 = kv; i2 = i;
      }
    }
    int ptr = 0;
    for (int r = 0; r < 3; ++r) {
      float mv = (ptr == 0) ? v0 : (ptr == 1) ? v1 : (ptr == 2) ? v2 : -1.f;
      int   mi = (ptr == 0) ? i0 : (ptr == 1) ? i1 : (ptr == 2) ? i2 : 0x7fffffff;
      float bv = mv; int bi = mi;
#pragma unroll
      for (int off = 32; off; off >>= 1) {
        float ov = __shfl_xor(bv, off, 64);
        int   oi = __shfl_xor(bi, off, 64);
        if (ov > bv || (ov == bv && oi < bi)) { bv = ov; bi = oi; }
      }
      if (bi == mi && ptr < 3) ptr++;             // winner's owner pops
      if (lane == 0) sel[r] = (bi == 0x7fffffff) ? -1 : bi;
    }
  }
  __syncthreads();
  if (wid < 3) {
    int node = sel[wid];
    float v = 0.f;
    if (node >= 0) {
      v = h[(size_t)node * 64 + lane];
      for (int k2 = 2; k2 <= 64; k2 <<= 1) {
        for (int j = k2 >> 1; j > 0; j >>= 1) {
          float o = __shfl_xor(v, j, 64);
          bool up = ((lane & k2) == 0);
          bool lower = ((lane & j) == 0);
          v = (lower == up) ? fminf(v, o) : fmaxf(v, o);
        }
      }
    }
    prow[wid * 64 + lane] = v;
  }
  __syncthreads();
  if (wid == 0) {
    float y = cb[lane];
    for (int j = 0; j < 192; ++j) y = fmaf(prow[j], cw[lane * 192 + j], y);
    float ry = fmaxf(y, 0.f);
    for (int c = 0; c < 10; ++c) {
      float s = ry * Wc[lane * 10 + c];
#pragma unroll
      for (int off = 32; off; off >>= 1) s += __shfl_xor(s, off, 64);
      if (lane == 0) out[b * 10 + c] = s + bc[c];
    }
  }
}

// ================================================================ launch
extern "C" void kernel_launch(void* const* d_in, const int* in_sizes, int n_in,
                              void* d_out, int out_size, void* d_ws, size_t ws_size,
                              hipStream_t stream) {
  const float* features = (const float*)d_in[0];
  const int*   esrc     = (const int*)d_in[1];
  const int*   edst     = (const int*)d_in[2];
  const int*   gid      = (const int*)d_in[3];
  const float* W1 = (const float*)d_in[5];
  const float* b1 = (const float*)d_in[6];
  const float* W2 = (const float*)d_in[7];
  const float* b2 = (const float*)d_in[8];
  const float* cw = (const float*)d_in[9];
  const float* cb = (const float*)d_in[10];
  const float* Wc = (const float*)d_in[11];
  const float* bc = (const float*)d_in[12];
  float* out = (float*)d_out;

  const int N = in_sizes[0] / 64;
  const int E = in_sizes[1];
  const int B = out_size / 10;
  const size_t N64 = (size_t)N * 64;
  const int nscan = (N + 2047) / 2048;          // <= 64 for N <= 131072
  const int PH = (N + PART_H - 1) / PART_H;     // 4 for N=100k
  const int PF = (N + PART_F - 1) / PART_F;     // 8 for N=100k -> XCD pin
  const size_t HSZ = (size_t)PH * MCH * PART_H; // u8 hist bytes (~6.4 MB)
  const int NT = (N + 127) / 128;               // gemm tiles
  const int histBlocks = 2 * PH * MCH;          // 512

  // workspace carve-up (~75 MB of the 256 MB ws; fully disjoint).
  float* bufA   = (float*)d_ws;            // N*64 : m1 -> m2
  float* bufB   = bufA + N64;              // N*64 : h1 -> h2
  int*   deg_d  = (int*)(bufB + N64);      // N
  float* norm_s = (float*)(deg_d + N);     // N
  float* norm_d = norm_s + N;              // N
  float* key    = norm_d + N;              // N
  int*   rowptr = (int*)(key + N);         // N
  int*   csr    = rowptr + N;              // E
  int*   bsum   = csr + E;                 // <=64
  int*   gstart = bsum + 64;               // B
  int*   gcnt   = gstart + B;              // B
  unsigned char* hd = (unsigned char*)(gcnt + B);    // HSZ u8
  unsigned char* hs = hd + HSZ;                      // HSZ u8

  const int TB = 256;

  // gstart sentinel fill (consumed by gather2's fused bstart + k_bfin)
  hipMemsetAsync(gstart, 0x7f, (size_t)B * sizeof(int), stream);

  // ---- CSR build overlapped with gemm1 (gemm1 emits un-normed product;
  //      norm_s is applied per-source inside gather1)
  k_histgemm<<<histBlocks + NT, TB, 0, stream>>>(esrc, edst, hd, hs,
                                                 features, W1, bufA,
                                                 N, E, PH, histBlocks);
  k_off<<<(N + TB - 1) / TB, TB, 0, stream>>>(hd, hs, deg_d, norm_s, norm_d, N);
  k_scan1<<<nscan, 256, 0, stream>>>(deg_d, rowptr, bsum, N);
  k_scan2<<<1, 64, 0, stream>>>(bsum, nscan);
  k_scan3<<<(N + TB - 1) / TB, TB, 0, stream>>>(rowptr, bsum, N);
  k_fill2<<<PF * MCH, TB, 0, stream>>>(esrc, edst, hd, rowptr, csr, N, E, PF);

  // ---- layer 1 gather (applies norm_s per source)
  k_gather<<<(N + 3) / 4, TB, 0, stream>>>(bufA, rowptr, deg_d, norm_d, b1, csr,
                                           norm_s, nullptr, nullptr,
                                           bufB, nullptr, N);

  // ---- layer 2
  k_gemm64<<<NT, TB, 0, stream>>>(bufB, norm_s, W2, bufA, N);
  k_gather<<<(N + 3) / 4, TB, 0, stream>>>(bufA, rowptr, deg_d, norm_d, b2, csr,
                                           nullptr, gid, gstart,
                                           bufB, key, N);

  // ---- pooling + classifier
  k_bfin<<<1, 512, 0, stream>>>(gstart, gcnt, B, N);
  k_tail<<<B, TB, 0, stream>>>(key, gstart, gcnt, bufB, cw, cb, Wc, bc, out, B, N);
}

// Round 14
// 302.910 us; speedup vs baseline: 1.0834x; 1.0140x over previous
//
#include <hip/hip_runtime.h>
#include <hip/hip_bf16.h>

// Problem constants (reference): IN_DIM = HID = 64, K = 3, NCLS = 10.
// All compute fp32. Output fp32 (B*10).
//
// Pipeline:
//   k_histgemm : heterogeneous grid — histogram blocks (u8-packed LDS
//                counters, PART_H=50176, PH=2 -> edge re-reads halved vs
//                R13) + gemm1 tiles (norm_s deferred into gather1).
//   k_off/scan : u8 chunk offsets in place + rowptr scan.
//   k_fill2    : u8-packed LDS cursors, PART_F=25088, PF=4 (edge re-reads
//                halved; csr span/partition 1.2MB still L2-merged).
//   k_gather   : 8 edge-groups x 2-deep (deg~12 fully in flight in one
//                round — tests whether 3.08 TB/s was MLP- or fabric-bound).
//   k_tail     : per-graph top3 + bitonic sort-pool + classifier.

#define PART_H 50176
#define QPART_H (PART_H / 4)
#define PART_F 25088
#define QUART_F (PART_F / 4)
#define MCH  64

// ---------------- fused histogram + gemm1 (independent workloads, one grid)
__global__ void __launch_bounds__(256) k_histgemm(
    const int* __restrict__ esrc, const int* __restrict__ edst,
    unsigned char* __restrict__ hd, unsigned char* __restrict__ hs,
    const float* __restrict__ in, const float* __restrict__ W,
    float* __restrict__ mout, int N, int E, int PH, int histBlocks) {
  __shared__ float smem[12800];   // 51.2 KB union: hist counters / Wl+Ac
  const int t = threadIdx.x;
  if (blockIdx.x < histBlocks) {
    unsigned int* lc = (unsigned int*)smem;       // QPART_H u32 = 50176 B
    const int b = blockIdx.x;
    const int half = PH * MCH;
    const int a = b / half;
    const int r = b % half;
    const int p = r % PH;
    const int m = r / PH;
    const int* __restrict__ arr = a ? esrc : edst;
    unsigned char* __restrict__ outp = a ? hs : hd;
    const int base = p * PART_H;
    const int lim = min(PART_H, N - base);
    for (int i = t; i < QPART_H; i += 256) lc[i] = 0u;
    __syncthreads();
    const long long cb = (long long)m * E / MCH;
    const long long ce = (long long)(m + 1) * E / MCH;
    const long long a0 = min((cb + 3) & ~3LL, ce);
    const long long nv = (ce - a0) >> 2;
    for (long long e = cb + t; e < a0; e += 256) {
      int d = arr[e] - base;
      if ((unsigned)d < (unsigned)lim) atomicAdd(&lc[d >> 2], 1u << ((d & 3) * 8));
    }
    const int4* __restrict__ a4p = (const int4*)(arr + a0);
    for (long long i = t; i < nv; i += 256) {
      int4 v4 = a4p[i];
      int d;
      d = v4.x - base; if ((unsigned)d < (unsigned)lim) atomicAdd(&lc[d >> 2], 1u << ((d & 3) * 8));
      d = v4.y - base; if ((unsigned)d < (unsigned)lim) atomicAdd(&lc[d >> 2], 1u << ((d & 3) * 8));
      d = v4.z - base; if ((unsigned)d < (unsigned)lim) atomicAdd(&lc[d >> 2], 1u << ((d & 3) * 8));
      d = v4.w - base; if ((unsigned)d < (unsigned)lim) atomicAdd(&lc[d >> 2], 1u << ((d & 3) * 8));
    }
    for (long long e = a0 + (nv << 2) + t; e < ce; e += 256) {
      int d = arr[e] - base;
      if ((unsigned)d < (unsigned)lim) atomicAdd(&lc[d >> 2], 1u << ((d & 3) * 8));
    }
    __syncthreads();
    unsigned char* slice = outp + ((size_t)p * MCH + m) * PART_H;
    for (int i = t; i < lim; i += 256)
      slice[i] = (unsigned char)((lc[i >> 2] >> ((i & 3) * 8)) & 0xffu);
  } else {
    float* Wl = smem;             // 4096 floats
    float* Ac = smem + 4096;      // 64*136 = 8704 floats
    const int ch = (t & 7) * 8;
    const int nb = (t >> 3) * 4;
    for (int i = t; i < 1024; i += 256)
      ((float4*)Wl)[i] = ((const float4*)W)[i];
    const int gb = blockIdx.x - histBlocks;
    const int ng = gridDim.x - histBlocks;
    const int NT = (N + 127) >> 7;
    for (int tile = gb; tile < NT; tile += ng) {
      const int vbase = tile << 7;
      __syncthreads();
      for (int i = t; i < 2048; i += 256) {
        const int r = i >> 4;
        const int c = (i & 15) * 4;
        const int v = vbase + r;
        float4 val = make_float4(0.f, 0.f, 0.f, 0.f);
        if (v < N) val = *(const float4*)(in + (size_t)v * 64 + c);
        Ac[(c + 0) * 136 + r] = val.x;
        Ac[(c + 1) * 136 + r] = val.y;
        Ac[(c + 2) * 136 + r] = val.z;
        Ac[(c + 3) * 136 + r] = val.w;
      }
      __syncthreads();
      float acc[4][8];
#pragma unroll
      for (int j = 0; j < 4; ++j)
#pragma unroll
        for (int c = 0; c < 8; ++c) acc[j][c] = 0.f;
      for (int k = 0; k < 64; k += 4) {
#pragma unroll
        for (int kk = 0; kk < 4; ++kk) {
          const float4 aa = *(const float4*)&Ac[(k + kk) * 136 + nb];
          const float4 w0 = *(const float4*)&Wl[(k + kk) * 64 + ch];
          const float4 w1 = *(const float4*)&Wl[(k + kk) * 64 + ch + 4];
          const float an[4] = {aa.x, aa.y, aa.z, aa.w};
          const float wn[8] = {w0.x, w0.y, w0.z, w0.w, w1.x, w1.y, w1.z, w1.w};
#pragma unroll
          for (int j = 0; j < 4; ++j)
#pragma unroll
            for (int c = 0; c < 8; ++c)
              acc[j][c] = fmaf(an[j], wn[c], acc[j][c]);
        }
      }
#pragma unroll
      for (int j = 0; j < 4; ++j) {
        const int v = vbase + nb + j;
        if (v < N) {
          float4 o0, o1;
          o0.x = acc[j][0]; o0.y = acc[j][1]; o0.z = acc[j][2]; o0.w = acc[j][3];
          o1.x = acc[j][4]; o1.y = acc[j][5]; o1.z = acc[j][6]; o1.w = acc[j][7];
          *(float4*)(mout + (size_t)v * 64 + ch)     = o0;
          *(float4*)(mout + (size_t)v * 64 + ch + 4) = o1;
        }
      }
    }
  }
}

// ---------------- counts -> in-row prefix offsets (u8, in place) + degs/norms
__global__ void k_off(unsigned char* __restrict__ hd, const unsigned char* __restrict__ hs,
                      int* __restrict__ deg_d, float* __restrict__ norm_s,
                      float* __restrict__ norm_d, int N) {
  int v = blockIdx.x * blockDim.x + threadIdx.x;
  if (v >= N) return;
  size_t base = (size_t)(v / PART_H) * MCH * PART_H + (v % PART_H);
  int run = 0;
#pragma unroll
  for (int m = 0; m < MCH; ++m) {
    int t = hd[base + (size_t)m * PART_H];
    hd[base + (size_t)m * PART_H] = (unsigned char)run;
    run += t;
  }
  int s = 0;
#pragma unroll
  for (int m = 0; m < MCH; ++m) s += hs[base + (size_t)m * PART_H];
  deg_d[v] = run;
  norm_d[v] = rsqrtf((float)max(run, 1));
  norm_s[v] = rsqrtf((float)max(s, 1));
}

// ------------------------------------------------------------ CSR scan
__global__ void k_scan1(const int* __restrict__ deg, int* __restrict__ rowptr,
                        int* __restrict__ bsum, int N) {
  __shared__ int sums[256];
  const int t = threadIdx.x;
  const int base = blockIdx.x * 2048 + t * 8;
  int loc[8];
  int tot = 0;
#pragma unroll
  for (int j = 0; j < 8; ++j) {
    int idx = base + j;
    loc[j] = tot;
    tot += (idx < N) ? deg[idx] : 0;
  }
  sums[t] = tot;
  __syncthreads();
  for (int off = 1; off < 256; off <<= 1) {
    int x = (t >= off) ? sums[t - off] : 0;
    __syncthreads();
    sums[t] += x;
    __syncthreads();
  }
  int excl = (t == 0) ? 0 : sums[t - 1];
#pragma unroll
  for (int j = 0; j < 8; ++j) {
    int idx = base + j;
    if (idx < N) rowptr[idx] = excl + loc[j];
  }
  if (t == 255) bsum[blockIdx.x] = sums[255];
}

__global__ void k_scan2(int* __restrict__ bsum, int nb) {
  int lane = threadIdx.x;
  int v = (lane < nb) ? bsum[lane] : 0;
  int inc = v;
#pragma unroll
  for (int off = 1; off < 64; off <<= 1) {
    int o = __shfl_up(inc, off, 64);
    if (lane >= off) inc += o;
  }
  if (lane < nb) bsum[lane] = inc - v;
}

__global__ void k_scan3(int* __restrict__ rowptr, const int* __restrict__ bsum, int N) {
  int v = blockIdx.x * blockDim.x + threadIdx.x;
  if (v < N) rowptr[v] += bsum[v >> 11];
}

// --------------------------- fill (u8-packed LDS cursors, no global atomics)
__global__ void k_fill2(const int* __restrict__ esrc, const int* __restrict__ edst,
                        const unsigned char* __restrict__ hd, const int* __restrict__ rowptr,
                        int* __restrict__ csr, int N, int E, int PF) {
  __shared__ unsigned int cur4[QUART_F];
  const int b = blockIdx.x;
  const int p = b % PF;
  const int m = b / PF;
  const int base = p * PART_F;
  const int lim = min(PART_F, N - base);
  // PART_H == 2*PART_F: hist partition = p>>1, offset = (p&1)*PART_F
  const unsigned char* slice = hd + ((size_t)(p >> 1) * MCH + m) * PART_H
                                  + (size_t)(p & 1) * PART_F;
  const unsigned int* slice4 = (const unsigned int*)slice;
  for (int i = threadIdx.x; i < QUART_F; i += blockDim.x) cur4[i] = slice4[i];
  __syncthreads();
  const int* __restrict__ rp = rowptr + base;
  const long long cb = (long long)m * E / MCH;
  const long long ce = (long long)(m + 1) * E / MCH;
  const long long a0 = min((cb + 3) & ~3LL, ce);
  const long long nv = (ce - a0) >> 2;
  for (long long e = cb + threadIdx.x; e < a0; e += blockDim.x) {
    int d = edst[e] - base;
    if ((unsigned)d < (unsigned)lim) {
      unsigned int old = atomicAdd(&cur4[d >> 2], 1u << ((d & 3) * 8));
      csr[rp[d] + ((old >> ((d & 3) * 8)) & 0xff)] = esrc[e];
    }
  }
  const int4* __restrict__ d4p = (const int4*)(edst + a0);
  const int4* __restrict__ s4p = (const int4*)(esrc + a0);
  for (long long i = threadIdx.x; i < nv; i += blockDim.x) {
    int4 d4 = d4p[i];
    int4 s4 = s4p[i];
    int d;
    d = d4.x - base;
    if ((unsigned)d < (unsigned)lim) {
      unsigned int old = atomicAdd(&cur4[d >> 2], 1u << ((d & 3) * 8));
      csr[rp[d] + ((old >> ((d & 3) * 8)) & 0xff)] = s4.x;
    }
    d = d4.y - base;
    if ((unsigned)d < (unsigned)lim) {
      unsigned int old = atomicAdd(&cur4[d >> 2], 1u << ((d & 3) * 8));
      csr[rp[d] + ((old >> ((d & 3) * 8)) & 0xff)] = s4.y;
    }
    d = d4.z - base;
    if ((unsigned)d < (unsigned)lim) {
      unsigned int old = atomicAdd(&cur4[d >> 2], 1u << ((d & 3) * 8));
      csr[rp[d] + ((old >> ((d & 3) * 8)) & 0xff)] = s4.z;
    }
    d = d4.w - base;
    if ((unsigned)d < (unsigned)lim) {
      unsigned int old = atomicAdd(&cur4[d >> 2], 1u << ((d & 3) * 8));
      csr[rp[d] + ((old >> ((d & 3) * 8)) & 0xff)] = s4.w;
    }
  }
  for (long long e = a0 + (nv << 2) + threadIdx.x; e < ce; e += blockDim.x) {
    int d = edst[e] - base;
    if ((unsigned)d < (unsigned)lim) {
      unsigned int old = atomicAdd(&cur4[d >> 2], 1u << ((d & 3) * 8));
      csr[rp[d] + ((old >> ((d & 3) * 8)) & 0xff)] = esrc[e];
    }
  }
}

// ------------------------------------------------- (N,64) @ (64,64) GEMM
// (layer 2 only; applies norm at store)
__global__ void __launch_bounds__(256) k_gemm64(
    const float* __restrict__ in, const float* __restrict__ norm,
    const float* __restrict__ W, float* __restrict__ out, int N) {
  __shared__ float Wl[4096];
  __shared__ float Ac[64 * 136];
  const int t = threadIdx.x;
  const int ch = (t & 7) * 8;
  const int nb = (t >> 3) * 4;
  for (int i = t; i < 1024; i += 256)
    ((float4*)Wl)[i] = ((const float4*)W)[i];
  const int NT = (N + 127) >> 7;
  for (int tile = blockIdx.x; tile < NT; tile += gridDim.x) {
    const int vbase = tile << 7;
    __syncthreads();
    for (int i = t; i < 2048; i += 256) {
      const int r = i >> 4;
      const int c = (i & 15) * 4;
      const int v = vbase + r;
      float4 val = make_float4(0.f, 0.f, 0.f, 0.f);
      if (v < N) val = *(const float4*)(in + (size_t)v * 64 + c);
      Ac[(c + 0) * 136 + r] = val.x;
      Ac[(c + 1) * 136 + r] = val.y;
      Ac[(c + 2) * 136 + r] = val.z;
      Ac[(c + 3) * 136 + r] = val.w;
    }
    __syncthreads();
    float acc[4][8];
#pragma unroll
    for (int j = 0; j < 4; ++j)
#pragma unroll
      for (int c = 0; c < 8; ++c) acc[j][c] = 0.f;
    for (int k = 0; k < 64; k += 4) {
#pragma unroll
      for (int kk = 0; kk < 4; ++kk) {
        const float4 aa = *(const float4*)&Ac[(k + kk) * 136 + nb];
        const float4 w0 = *(const float4*)&Wl[(k + kk) * 64 + ch];
        const float4 w1 = *(const float4*)&Wl[(k + kk) * 64 + ch + 4];
        const float an[4] = {aa.x, aa.y, aa.z, aa.w};
        const float wn[8] = {w0.x, w0.y, w0.z, w0.w, w1.x, w1.y, w1.z, w1.w};
#pragma unroll
        for (int j = 0; j < 4; ++j)
#pragma unroll
          for (int c = 0; c < 8; ++c)
            acc[j][c] = fmaf(an[j], wn[c], acc[j][c]);
      }
    }
#pragma unroll
    for (int j = 0; j < 4; ++j) {
      const int v = vbase + nb + j;
      if (v < N) {
        const float nm = norm[v];
        float4 o0, o1;
        o0.x = acc[j][0] * nm; o0.y = acc[j][1] * nm;
        o0.z = acc[j][2] * nm; o0.w = acc[j][3] * nm;
        o1.x = acc[j][4] * nm; o1.y = acc[j][5] * nm;
        o1.z = acc[j][6] * nm; o1.w = acc[j][7] * nm;
        *(float4*)(out + (size_t)v * 64 + ch)     = o0;
        *(float4*)(out + (size_t)v * 64 + ch + 4) = o1;
      }
    }
  }
}

// ---------------------------------------- CSR gather + fused epilogue
// 8 edge-groups of 8 lanes; each lane owns 8 channels (2 x float4).
// 2-deep unroll (edges i, i+8) -> deg<=16 fully in flight in one round.
// nsrc != nullptr: per-source norm_s (layer 1).
// gid/gstart != nullptr: fused sorted-gid boundary detection (layer 2).
__global__ void k_gather(const float* __restrict__ m, const int* __restrict__ rowptr,
                         const int* __restrict__ deg, const float* __restrict__ norm_d,
                         const float* __restrict__ bias, const int* __restrict__ csr,
                         const float* __restrict__ nsrc,
                         const int* __restrict__ gid, int* __restrict__ gstart,
                         float* __restrict__ h, float* __restrict__ key, int N) {
  const int w = blockIdx.x * (blockDim.x >> 6) + (threadIdx.x >> 6);
  if (w >= N) return;
  const int lane = threadIdx.x & 63;
  const int chb = (lane & 7) * 8;   // channel base (8 ch/lane)
  const int grp = lane >> 3;        // 8 edge subgroups
  if (gid != nullptr && lane == 0) {
    int g = gid[w];
    if (w == 0 || gid[w - 1] != g) gstart[g] = w;
  }
  const int start = rowptr[w];
  const int cnt = deg[w];
  float4 a00 = make_float4(0.f, 0.f, 0.f, 0.f);
  float4 a01 = make_float4(0.f, 0.f, 0.f, 0.f);
  float4 a10 = make_float4(0.f, 0.f, 0.f, 0.f);
  float4 a11 = make_float4(0.f, 0.f, 0.f, 0.f);
  int i = grp;
  if (nsrc != nullptr) {
    for (; i + 8 < cnt; i += 16) {
      int s0 = csr[start + i];
      int s1 = csr[start + i + 8];
      float n0 = nsrc[s0], n1 = nsrc[s1];
      const float* r0 = m + (size_t)s0 * 64 + chb;
      const float* r1 = m + (size_t)s1 * 64 + chb;
      const float4 v00 = *(const float4*)r0;
      const float4 v01 = *(const float4*)(r0 + 4);
      const float4 v10 = *(const float4*)r1;
      const float4 v11 = *(const float4*)(r1 + 4);
      a00.x = fmaf(v00.x, n0, a00.x); a00.y = fmaf(v00.y, n0, a00.y);
      a00.z = fmaf(v00.z, n0, a00.z); a00.w = fmaf(v00.w, n0, a00.w);
      a01.x = fmaf(v01.x, n0, a01.x); a01.y = fmaf(v01.y, n0, a01.y);
      a01.z = fmaf(v01.z, n0, a01.z); a01.w = fmaf(v01.w, n0, a01.w);
      a10.x = fmaf(v10.x, n1, a10.x); a10.y = fmaf(v10.y, n1, a10.y);
      a10.z = fmaf(v10.z, n1, a10.z); a10.w = fmaf(v10.w, n1, a10.w);
      a11.x = fmaf(v11.x, n1, a11.x); a11.y = fmaf(v11.y, n1, a11.y);
      a11.z = fmaf(v11.z, n1, a11.z); a11.w = fmaf(v11.w, n1, a11.w);
    }
    if (i < cnt) {
      int s0 = csr[start + i];
      float n0 = nsrc[s0];
      const float* r0 = m + (size_t)s0 * 64 + chb;
      const float4 v00 = *(const float4*)r0;
      const float4 v01 = *(const float4*)(r0 + 4);
      a00.x = fmaf(v00.x, n0, a00.x); a00.y = fmaf(v00.y, n0, a00.y);
      a00.z = fmaf(v00.z, n0, a00.z); a00.w = fmaf(v00.w, n0, a00.w);
      a01.x = fmaf(v01.x, n0, a01.x); a01.y = fmaf(v01.y, n0, a01.y);
      a01.z = fmaf(v01.z, n0, a01.z); a01.w = fmaf(v01.w, n0, a01.w);
    }
  } else {
    for (; i + 8 < cnt; i += 16) {
      int s0 = csr[start + i];
      int s1 = csr[start + i + 8];
      const float* r0 = m + (size_t)s0 * 64 + chb;
      const float* r1 = m + (size_t)s1 * 64 + chb;
      const float4 v00 = *(const float4*)r0;
      const float4 v01 = *(const float4*)(r0 + 4);
      const float4 v10 = *(const float4*)r1;
      const float4 v11 = *(const float4*)(r1 + 4);
      a00.x += v00.x; a00.y += v00.y; a00.z += v00.z; a00.w += v00.w;
      a01.x += v01.x; a01.y += v01.y; a01.z += v01.z; a01.w += v01.w;
      a10.x += v10.x; a10.y += v10.y; a10.z += v10.z; a10.w += v10.w;
      a11.x += v11.x; a11.y += v11.y; a11.z += v11.z; a11.w += v11.w;
    }
    if (i < cnt) {
      int s0 = csr[start + i];
      const float* r0 = m + (size_t)s0 * 64 + chb;
      const float4 v00 = *(const float4*)r0;
      const float4 v01 = *(const float4*)(r0 + 4);
      a00.x += v00.x; a00.y += v00.y; a00.z += v00.z; a00.w += v00.w;
      a01.x += v01.x; a01.y += v01.y; a01.z += v01.z; a01.w += v01.w;
    }
  }
  a00.x += a10.x; a00.y += a10.y; a00.z += a10.z; a00.w += a10.w;
  a01.x += a11.x; a01.y += a11.y; a01.z += a11.z; a01.w += a11.w;
  // reduce across the 8 edge subgroups (lanes differing in bits 3..5)
#pragma unroll
  for (int off = 8; off <= 32; off <<= 1) {
    a00.x += __shfl_xor(a00.x, off, 64);
    a00.y += __shfl_xor(a00.y, off, 64);
    a00.z += __shfl_xor(a00.z, off, 64);
    a00.w += __shfl_xor(a00.w, off, 64);
    a01.x += __shfl_xor(a01.x, off, 64);
    a01.y += __shfl_xor(a01.y, off, 64);
    a01.z += __shfl_xor(a01.z, off, 64);
    a01.w += __shfl_xor(a01.w, off, 64);
  }
  const float nd = norm_d[w];
  const float4 b0 = *(const float4*)(bias + chb);
  const float4 b1 = *(const float4*)(bias + chb + 4);
  float4 o0, o1;
  o0.x = fmaxf(fmaf(a00.x, nd, b0.x), 0.f);
  o0.y = fmaxf(fmaf(a00.y, nd, b0.y), 0.f);
  o0.z = fmaxf(fmaf(a00.z, nd, b0.z), 0.f);
  o0.w = fmaxf(fmaf(a00.w, nd, b0.w), 0.f);
  o1.x = fmaxf(fmaf(a01.x, nd, b1.x), 0.f);
  o1.y = fmaxf(fmaf(a01.y, nd, b1.y), 0.f);
  o1.z = fmaxf(fmaf(a01.z, nd, b1.z), 0.f);
  o1.w = fmaxf(fmaf(a01.w, nd, b1.w), 0.f);
  if (grp == 0) {
    *(float4*)(h + (size_t)w * 64 + chb)     = o0;
    *(float4*)(h + (size_t)w * 64 + chb + 4) = o1;
  }
  if (key != nullptr) {
    float mx = fmaxf(fmaxf(fmaxf(o0.x, o0.y), fmaxf(o0.z, o0.w)),
                     fmaxf(fmaxf(o1.x, o1.y), fmaxf(o1.z, o1.w)));
#pragma unroll
    for (int off = 1; off < 8; off <<= 1) mx = fmaxf(mx, __shfl_xor(mx, off, 64));
    if (lane == 0) key[w] = mx;
  }
}

// ------------------- gcnt via suffix-min over gstart (one 512-thread block)
__global__ void k_bfin(const int* __restrict__ gstart, int* __restrict__ gcnt,
                       int B, int N) {
  __shared__ int sm[512];
  const int g = threadIdx.x;
  sm[g] = (g < B) ? gstart[g] : 0x7fffffff;
  __syncthreads();
  for (int off = 1; off < 512; off <<= 1) {
    int x = (g + off < 512) ? sm[g + off] : 0x7fffffff;
    __syncthreads();
    sm[g] = min(sm[g], x);
    __syncthreads();
  }
  if (g < B) {
    int gs = gstart[g];
    int ns = (g + 1 < 512) ? min(sm[g + 1], N) : N;
    gcnt[g] = (gs < N) ? (ns - gs) : 0;
  }
}

// ---------------- fused tail: per-graph top3 + bitonic sort-pool + classifier
__global__ void __launch_bounds__(256) k_tail(
    const float* __restrict__ key, const int* __restrict__ gstart,
    const int* __restrict__ gcnt, const float* __restrict__ h,
    const float* __restrict__ cw, const float* __restrict__ cb,
    const float* __restrict__ Wc, const float* __restrict__ bc,
    float* __restrict__ out, int B, int N) {
  __shared__ int sel[3];
  __shared__ float prow[192];
  const int b = blockIdx.x;
  const int wid = threadIdx.x >> 6;
  const int lane = threadIdx.x & 63;

  if (wid == 0) {
    const int s = gstart[b], c = gcnt[b];
    float v0 = -1.f, v1 = -1.f, v2 = -1.f;
    int i0 = 0x7fffffff, i1 = 0x7fffffff, i2 = 0x7fffffff;
    for (int i = s + lane; i < s + c; i += 64) {
      float kv = key[i];
      if (kv > v0 || (kv == v0 && i < i0)) {
        v2 = v1; i2 = i1; v1 = v0; i1 = i0; v0 = kv; i0 = i;
      } else if (kv > v1 || (kv == v1 && i < i1)) {
        v2 = v1; i2 = i1; v1 = kv; i1 = i;
      } else if (kv > v2 || (kv == v2 && i < i2)) {
        v2 = kv; i2 = i;
      }
    }
    int ptr = 0;
    for (int r = 0; r < 3; ++r) {
      float mv = (ptr == 0) ? v0 : (ptr == 1) ? v1 : (ptr == 2) ? v2 : -1.f;
      int   mi = (ptr == 0) ? i0 : (ptr == 1) ? i1 : (ptr == 2) ? i2 : 0x7fffffff;
      float bv = mv; int bi = mi;
#pragma unroll
      for (int off = 32; off; off >>= 1) {
        float ov = __shfl_xor(bv, off, 64);
        int   oi = __shfl_xor(bi, off, 64);
        if (ov > bv || (ov == bv && oi < bi)) { bv = ov; bi = oi; }
      }
      if (bi == mi && ptr < 3) ptr++;             // winner's owner pops
      if (lane == 0) sel[r] = (bi == 0x7fffffff) ? -1 : bi;
    }
  }
  __syncthreads();
  if (wid < 3) {
    int node = sel[wid];
    float v = 0.f;
    if (node >= 0) {
      v = h[(size_t)node * 64 + lane];
      for (int k2 = 2; k2 <= 64; k2 <<= 1) {
        for (int j = k2 >> 1; j > 0; j >>= 1) {
          float o = __shfl_xor(v, j, 64);
          bool up = ((lane & k2) == 0);
          bool lower = ((lane & j) == 0);
          v = (lower == up) ? fminf(v, o) : fmaxf(v, o);
        }
      }
    }
    prow[wid * 64 + lane] = v;
  }
  __syncthreads();
  if (wid == 0) {
    float y = cb[lane];
    for (int j = 0; j < 192; ++j) y = fmaf(prow[j], cw[lane * 192 + j], y);
    float ry = fmaxf(y, 0.f);
    for (int c = 0; c < 10; ++c) {
      float s = ry * Wc[lane * 10 + c];
#pragma unroll
      for (int off = 32; off; off >>= 1) s += __shfl_xor(s, off, 64);
      if (lane == 0) out[b * 10 + c] = s + bc[c];
    }
  }
}

// ================================================================ launch
extern "C" void kernel_launch(void* const* d_in, const int* in_sizes, int n_in,
                              void* d_out, int out_size, void* d_ws, size_t ws_size,
                              hipStream_t stream) {
  const float* features = (const float*)d_in[0];
  const int*   esrc     = (const int*)d_in[1];
  const int*   edst     = (const int*)d_in[2];
  const int*   gid      = (const int*)d_in[3];
  const float* W1 = (const float*)d_in[5];
  const float* b1 = (const float*)d_in[6];
  const float* W2 = (const float*)d_in[7];
  const float* b2 = (const float*)d_in[8];
  const float* cw = (const float*)d_in[9];
  const float* cb = (const float*)d_in[10];
  const float* Wc = (const float*)d_in[11];
  const float* bc = (const float*)d_in[12];
  float* out = (float*)d_out;

  const int N = in_sizes[0] / 64;
  const int E = in_sizes[1];
  const int B = out_size / 10;
  const size_t N64 = (size_t)N * 64;
  const int nscan = (N + 2047) / 2048;          // <= 64 for N <= 131072
  const int PH = (N + PART_H - 1) / PART_H;     // 2 for N=100k
  const int PF = (N + PART_F - 1) / PART_F;     // 4 for N=100k
  const size_t HSZ = (size_t)PH * MCH * PART_H; // u8 hist bytes (~6.4 MB)
  const int NT = (N + 127) / 128;               // gemm tiles
  const int histBlocks = 2 * PH * MCH;          // 256

  // workspace carve-up (~75 MB of the 256 MB ws; fully disjoint).
  float* bufA   = (float*)d_ws;            // N*64 : m1 -> m2
  float* bufB   = bufA + N64;              // N*64 : h1 -> h2
  int*   deg_d  = (int*)(bufB + N64);      // N
  float* norm_s = (float*)(deg_d + N);     // N
  float* norm_d = norm_s + N;              // N
  float* key    = norm_d + N;              // N
  int*   rowptr = (int*)(key + N);         // N
  int*   csr    = rowptr + N;              // E
  int*   bsum   = csr + E;                 // <=64
  int*   gstart = bsum + 64;               // B
  int*   gcnt   = gstart + B;              // B
  unsigned char* hd = (unsigned char*)(gcnt + B);    // HSZ u8
  unsigned char* hs = hd + HSZ;                      // HSZ u8

  const int TB = 256;

  // gstart sentinel fill (consumed by gather2's fused bstart + k_bfin)
  hipMemsetAsync(gstart, 0x7f, (size_t)B * sizeof(int), stream);

  // ---- CSR build overlapped with gemm1 (un-normed; norm_s applied in gather1)
  k_histgemm<<<histBlocks + NT, TB, 0, stream>>>(esrc, edst, hd, hs,
                                                 features, W1, bufA,
                                                 N, E, PH, histBlocks);
  k_off<<<(N + TB - 1) / TB, TB, 0, stream>>>(hd, hs, deg_d, norm_s, norm_d, N);
  k_scan1<<<nscan, 256, 0, stream>>>(deg_d, rowptr, bsum, N);
  k_scan2<<<1, 64, 0, stream>>>(bsum, nscan);
  k_scan3<<<(N + TB - 1) / TB, TB, 0, stream>>>(rowptr, bsum, N);
  k_fill2<<<PF * MCH, TB, 0, stream>>>(esrc, edst, hd, rowptr, csr, N, E, PF);

  // ---- layer 1 gather (applies norm_s per source)
  k_gather<<<(N + 3) / 4, TB, 0, stream>>>(bufA, rowptr, deg_d, norm_d, b1, csr,
                                           norm_s, nullptr, nullptr,
                                           bufB, nullptr, N);

  // ---- layer 2
  k_gemm64<<<NT, TB, 0, stream>>>(bufB, norm_s, W2, bufA, N);
  k_gather<<<(N + 3) / 4, TB, 0, stream>>>(bufA, rowptr, deg_d, norm_d, b2, csr,
                                           nullptr, gid, gstart,
                                           bufB, key, N);

  // ---- pooling + classifier
  k_bfin<<<1, 512, 0, stream>>>(gstart, gcnt, B, N);
  k_tail<<<B, TB, 0, stream>>>(key, gstart, gcnt, bufB, cw, cb, Wc, bc, out, B, N);
}

// Round 15
// 299.541 us; speedup vs baseline: 1.0955x; 1.0112x over previous
//
#include <hip/hip_runtime.h>
#include <hip/hip_bf16.h>

// Problem constants (reference): IN_DIM = HID = 64, K = 3, NCLS = 10.
// All compute fp32. Output fp32 (B*10).
//
// Pipeline (9 dispatches, R14 consolidation):
//   k_histgemm : heterogeneous grid — u8-packed LDS histogram (PART_H=50176,
//                PH=2) + gemm1 tiles (norm_s deferred into gather1).
//   k_off      : u8 chunk offsets in place + deg/norms + gstart sentinels.
//   k_scan1/2  : block-local rowptr + exclusive block sums (consumers add
//                bsum[node>>11] at use — scan3 eliminated).
//   k_fill2    : u8-packed LDS cursors, PF=4.
//   k_gather   : fabric-floor bound (140 MB @ ~3.1 TB/s — confirmed R14:
//                doubling MLP was neutral).  gather1 applies norm_s per
//                source; gather2 fuses sorted-gid boundary detection.
//   k_gemm64   : LDS-tiled layer-2 GEMM.
//   k_tail     : per-graph top3 + bitonic sort-pool + classifier + fused
//                gcnt computation (bfin eliminated).

#define PART_H 50176
#define QPART_H (PART_H / 4)
#define PART_F 25088
#define QUART_F (PART_F / 4)
#define MCH  64

// ---------------- fused histogram + gemm1 (independent workloads, one grid)
__global__ void __launch_bounds__(256) k_histgemm(
    const int* __restrict__ esrc, const int* __restrict__ edst,
    unsigned char* __restrict__ hd, unsigned char* __restrict__ hs,
    const float* __restrict__ in, const float* __restrict__ W,
    float* __restrict__ mout, int N, int E, int PH, int histBlocks) {
  __shared__ float smem[12800];   // 51.2 KB union: hist counters / Wl+Ac
  const int t = threadIdx.x;
  if (blockIdx.x < histBlocks) {
    unsigned int* lc = (unsigned int*)smem;       // QPART_H u32 = 50176 B
    const int b = blockIdx.x;
    const int half = PH * MCH;
    const int a = b / half;
    const int r = b % half;
    const int p = r % PH;
    const int m = r / PH;
    const int* __restrict__ arr = a ? esrc : edst;
    unsigned char* __restrict__ outp = a ? hs : hd;
    const int base = p * PART_H;
    const int lim = min(PART_H, N - base);
    for (int i = t; i < QPART_H; i += 256) lc[i] = 0u;
    __syncthreads();
    const long long cb = (long long)m * E / MCH;
    const long long ce = (long long)(m + 1) * E / MCH;
    const long long a0 = min((cb + 3) & ~3LL, ce);
    const long long nv = (ce - a0) >> 2;
    for (long long e = cb + t; e < a0; e += 256) {
      int d = arr[e] - base;
      if ((unsigned)d < (unsigned)lim) atomicAdd(&lc[d >> 2], 1u << ((d & 3) * 8));
    }
    const int4* __restrict__ a4p = (const int4*)(arr + a0);
    for (long long i = t; i < nv; i += 256) {
      int4 v4 = a4p[i];
      int d;
      d = v4.x - base; if ((unsigned)d < (unsigned)lim) atomicAdd(&lc[d >> 2], 1u << ((d & 3) * 8));
      d = v4.y - base; if ((unsigned)d < (unsigned)lim) atomicAdd(&lc[d >> 2], 1u << ((d & 3) * 8));
      d = v4.z - base; if ((unsigned)d < (unsigned)lim) atomicAdd(&lc[d >> 2], 1u << ((d & 3) * 8));
      d = v4.w - base; if ((unsigned)d < (unsigned)lim) atomicAdd(&lc[d >> 2], 1u << ((d & 3) * 8));
    }
    for (long long e = a0 + (nv << 2) + t; e < ce; e += 256) {
      int d = arr[e] - base;
      if ((unsigned)d < (unsigned)lim) atomicAdd(&lc[d >> 2], 1u << ((d & 3) * 8));
    }
    __syncthreads();
    unsigned char* slice = outp + ((size_t)p * MCH + m) * PART_H;
    for (int i = t; i < lim; i += 256)
      slice[i] = (unsigned char)((lc[i >> 2] >> ((i & 3) * 8)) & 0xffu);
  } else {
    float* Wl = smem;             // 4096 floats
    float* Ac = smem + 4096;      // 64*136 = 8704 floats
    const int ch = (t & 7) * 8;
    const int nb = (t >> 3) * 4;
    for (int i = t; i < 1024; i += 256)
      ((float4*)Wl)[i] = ((const float4*)W)[i];
    const int gb = blockIdx.x - histBlocks;
    const int ng = gridDim.x - histBlocks;
    const int NT = (N + 127) >> 7;
    for (int tile = gb; tile < NT; tile += ng) {
      const int vbase = tile << 7;
      __syncthreads();
      for (int i = t; i < 2048; i += 256) {
        const int r = i >> 4;
        const int c = (i & 15) * 4;
        const int v = vbase + r;
        float4 val = make_float4(0.f, 0.f, 0.f, 0.f);
        if (v < N) val = *(const float4*)(in + (size_t)v * 64 + c);
        Ac[(c + 0) * 136 + r] = val.x;
        Ac[(c + 1) * 136 + r] = val.y;
        Ac[(c + 2) * 136 + r] = val.z;
        Ac[(c + 3) * 136 + r] = val.w;
      }
      __syncthreads();
      float acc[4][8];
#pragma unroll
      for (int j = 0; j < 4; ++j)
#pragma unroll
        for (int c = 0; c < 8; ++c) acc[j][c] = 0.f;
      for (int k = 0; k < 64; k += 4) {
#pragma unroll
        for (int kk = 0; kk < 4; ++kk) {
          const float4 aa = *(const float4*)&Ac[(k + kk) * 136 + nb];
          const float4 w0 = *(const float4*)&Wl[(k + kk) * 64 + ch];
          const float4 w1 = *(const float4*)&Wl[(k + kk) * 64 + ch + 4];
          const float an[4] = {aa.x, aa.y, aa.z, aa.w};
          const float wn[8] = {w0.x, w0.y, w0.z, w0.w, w1.x, w1.y, w1.z, w1.w};
#pragma unroll
          for (int j = 0; j < 4; ++j)
#pragma unroll
            for (int c = 0; c < 8; ++c)
              acc[j][c] = fmaf(an[j], wn[c], acc[j][c]);
        }
      }
#pragma unroll
      for (int j = 0; j < 4; ++j) {
        const int v = vbase + nb + j;
        if (v < N) {
          float4 o0, o1;
          o0.x = acc[j][0]; o0.y = acc[j][1]; o0.z = acc[j][2]; o0.w = acc[j][3];
          o1.x = acc[j][4]; o1.y = acc[j][5]; o1.z = acc[j][6]; o1.w = acc[j][7];
          *(float4*)(mout + (size_t)v * 64 + ch)     = o0;
          *(float4*)(mout + (size_t)v * 64 + ch + 4) = o1;
        }
      }
    }
  }
}

// ---------- counts -> in-row u8 prefix offsets + degs/norms + gstart sentinel
__global__ void k_off(unsigned char* __restrict__ hd, const unsigned char* __restrict__ hs,
                      int* __restrict__ deg_d, float* __restrict__ norm_s,
                      float* __restrict__ norm_d, int* __restrict__ gstart,
                      int B, int N) {
  int v = blockIdx.x * blockDim.x + threadIdx.x;
  if (v >= N) return;
  if (v < B) gstart[v] = 0x7f7f7f7f;   // sentinel (>= N)
  size_t base = (size_t)(v / PART_H) * MCH * PART_H + (v % PART_H);
  int run = 0;
#pragma unroll
  for (int m = 0; m < MCH; ++m) {
    int t = hd[base + (size_t)m * PART_H];
    hd[base + (size_t)m * PART_H] = (unsigned char)run;
    run += t;
  }
  int s = 0;
#pragma unroll
  for (int m = 0; m < MCH; ++m) s += hs[base + (size_t)m * PART_H];
  deg_d[v] = run;
  norm_d[v] = rsqrtf((float)max(run, 1));
  norm_s[v] = rsqrtf((float)max(s, 1));
}

// ------------------------------------------------------------ CSR scan
// rowptr gets BLOCK-LOCAL prefix; consumers add bsum[node>>11] (exclusive).
__global__ void k_scan1(const int* __restrict__ deg, int* __restrict__ rowptr,
                        int* __restrict__ bsum, int N) {
  __shared__ int sums[256];
  const int t = threadIdx.x;
  const int base = blockIdx.x * 2048 + t * 8;
  int loc[8];
  int tot = 0;
#pragma unroll
  for (int j = 0; j < 8; ++j) {
    int idx = base + j;
    loc[j] = tot;
    tot += (idx < N) ? deg[idx] : 0;
  }
  sums[t] = tot;
  __syncthreads();
  for (int off = 1; off < 256; off <<= 1) {
    int x = (t >= off) ? sums[t - off] : 0;
    __syncthreads();
    sums[t] += x;
    __syncthreads();
  }
  int excl = (t == 0) ? 0 : sums[t - 1];
#pragma unroll
  for (int j = 0; j < 8; ++j) {
    int idx = base + j;
    if (idx < N) rowptr[idx] = excl + loc[j];
  }
  if (t == 255) bsum[blockIdx.x] = sums[255];
}

__global__ void k_scan2(int* __restrict__ bsum, int nb) {
  int lane = threadIdx.x;
  int v = (lane < nb) ? bsum[lane] : 0;
  int inc = v;
#pragma unroll
  for (int off = 1; off < 64; off <<= 1) {
    int o = __shfl_up(inc, off, 64);
    if (lane >= off) inc += o;
  }
  if (lane < nb) bsum[lane] = inc - v;
}

// --------------------------- fill (u8-packed LDS cursors, no global atomics)
__global__ void k_fill2(const int* __restrict__ esrc, const int* __restrict__ edst,
                        const unsigned char* __restrict__ hd, const int* __restrict__ rowptr,
                        const int* __restrict__ bsum, int* __restrict__ csr,
                        int N, int E, int PF) {
  __shared__ unsigned int cur4[QUART_F];
  const int b = blockIdx.x;
  const int p = b % PF;
  const int m = b / PF;
  const int base = p * PART_F;
  const int lim = min(PART_F, N - base);
  // PART_H == 2*PART_F: hist partition = p>>1, offset = (p&1)*PART_F
  const unsigned char* slice = hd + ((size_t)(p >> 1) * MCH + m) * PART_H
                                  + (size_t)(p & 1) * PART_F;
  const unsigned int* slice4 = (const unsigned int*)slice;
  for (int i = threadIdx.x; i < QUART_F; i += blockDim.x) cur4[i] = slice4[i];
  __syncthreads();
  const int* __restrict__ rp = rowptr + base;
  const long long cb = (long long)m * E / MCH;
  const long long ce = (long long)(m + 1) * E / MCH;
  const long long a0 = min((cb + 3) & ~3LL, ce);
  const long long nv = (ce - a0) >> 2;
  for (long long e = cb + threadIdx.x; e < a0; e += blockDim.x) {
    int d = edst[e] - base;
    if ((unsigned)d < (unsigned)lim) {
      unsigned int old = atomicAdd(&cur4[d >> 2], 1u << ((d & 3) * 8));
      csr[rp[d] + bsum[(base + d) >> 11] + ((old >> ((d & 3) * 8)) & 0xff)] = esrc[e];
    }
  }
  const int4* __restrict__ d4p = (const int4*)(edst + a0);
  const int4* __restrict__ s4p = (const int4*)(esrc + a0);
  for (long long i = threadIdx.x; i < nv; i += blockDim.x) {
    int4 d4 = d4p[i];
    int4 s4 = s4p[i];
    int d;
    d = d4.x - base;
    if ((unsigned)d < (unsigned)lim) {
      unsigned int old = atomicAdd(&cur4[d >> 2], 1u << ((d & 3) * 8));
      csr[rp[d] + bsum[(base + d) >> 11] + ((old >> ((d & 3) * 8)) & 0xff)] = s4.x;
    }
    d = d4.y - base;
    if ((unsigned)d < (unsigned)lim) {
      unsigned int old = atomicAdd(&cur4[d >> 2], 1u << ((d & 3) * 8));
      csr[rp[d] + bsum[(base + d) >> 11] + ((old >> ((d & 3) * 8)) & 0xff)] = s4.y;
    }
    d = d4.z - base;
    if ((unsigned)d < (unsigned)lim) {
      unsigned int old = atomicAdd(&cur4[d >> 2], 1u << ((d & 3) * 8));
      csr[rp[d] + bsum[(base + d) >> 11] + ((old >> ((d & 3) * 8)) & 0xff)] = s4.z;
    }
    d = d4.w - base;
    if ((unsigned)d < (unsigned)lim) {
      unsigned int old = atomicAdd(&cur4[d >> 2], 1u << ((d & 3) * 8));
      csr[rp[d] + bsum[(base + d) >> 11] + ((old >> ((d & 3) * 8)) & 0xff)] = s4.w;
    }
  }
  for (long long e = a0 + (nv << 2) + threadIdx.x; e < ce; e += blockDim.x) {
    int d = edst[e] - base;
    if ((unsigned)d < (unsigned)lim) {
      unsigned int old = atomicAdd(&cur4[d >> 2], 1u << ((d & 3) * 8));
      csr[rp[d] + bsum[(base + d) >> 11] + ((old >> ((d & 3) * 8)) & 0xff)] = esrc[e];
    }
  }
}

// ------------------------------------------------- (N,64) @ (64,64) GEMM
// (layer 2 only; applies norm at store)
__global__ void __launch_bounds__(256) k_gemm64(
    const float* __restrict__ in, const float* __restrict__ norm,
    const float* __restrict__ W, float* __restrict__ out, int N) {
  __shared__ float Wl[4096];
  __shared__ float Ac[64 * 136];
  const int t = threadIdx.x;
  const int ch = (t & 7) * 8;
  const int nb = (t >> 3) * 4;
  for (int i = t; i < 1024; i += 256)
    ((float4*)Wl)[i] = ((const float4*)W)[i];
  const int NT = (N + 127) >> 7;
  for (int tile = blockIdx.x; tile < NT; tile += gridDim.x) {
    const int vbase = tile << 7;
    __syncthreads();
    for (int i = t; i < 2048; i += 256) {
      const int r = i >> 4;
      const int c = (i & 15) * 4;
      const int v = vbase + r;
      float4 val = make_float4(0.f, 0.f, 0.f, 0.f);
      if (v < N) val = *(const float4*)(in + (size_t)v * 64 + c);
      Ac[(c + 0) * 136 + r] = val.x;
      Ac[(c + 1) * 136 + r] = val.y;
      Ac[(c + 2) * 136 + r] = val.z;
      Ac[(c + 3) * 136 + r] = val.w;
    }
    __syncthreads();
    float acc[4][8];
#pragma unroll
    for (int j = 0; j < 4; ++j)
#pragma unroll
      for (int c = 0; c < 8; ++c) acc[j][c] = 0.f;
    for (int k = 0; k < 64; k += 4) {
#pragma unroll
      for (int kk = 0; kk < 4; ++kk) {
        const float4 aa = *(const float4*)&Ac[(k + kk) * 136 + nb];
        const float4 w0 = *(const float4*)&Wl[(k + kk) * 64 + ch];
        const float4 w1 = *(const float4*)&Wl[(k + kk) * 64 + ch + 4];
        const float an[4] = {aa.x, aa.y, aa.z, aa.w};
        const float wn[8] = {w0.x, w0.y, w0.z, w0.w, w1.x, w1.y, w1.z, w1.w};
#pragma unroll
        for (int j = 0; j < 4; ++j)
#pragma unroll
          for (int c = 0; c < 8; ++c)
            acc[j][c] = fmaf(an[j], wn[c], acc[j][c]);
      }
    }
#pragma unroll
    for (int j = 0; j < 4; ++j) {
      const int v = vbase + nb + j;
      if (v < N) {
        const float nm = norm[v];
        float4 o0, o1;
        o0.x = acc[j][0] * nm; o0.y = acc[j][1] * nm;
        o0.z = acc[j][2] * nm; o0.w = acc[j][3] * nm;
        o1.x = acc[j][4] * nm; o1.y = acc[j][5] * nm;
        o1.z = acc[j][6] * nm; o1.w = acc[j][7] * nm;
        *(float4*)(out + (size_t)v * 64 + ch)     = o0;
        *(float4*)(out + (size_t)v * 64 + ch + 4) = o1;
      }
    }
  }
}

// ---------------------------------------- CSR gather + fused epilogue
// 8 edge-groups of 8 lanes; each lane owns 8 channels (2 x float4).
__global__ void k_gather(const float* __restrict__ m, const int* __restrict__ rowptr,
                         const int* __restrict__ bsum,
                         const int* __restrict__ deg, const float* __restrict__ norm_d,
                         const float* __restrict__ bias, const int* __restrict__ csr,
                         const float* __restrict__ nsrc,
                         const int* __restrict__ gid, int* __restrict__ gstart,
                         float* __restrict__ h, float* __restrict__ key, int N) {
  const int w = blockIdx.x * (blockDim.x >> 6) + (threadIdx.x >> 6);
  if (w >= N) return;
  const int lane = threadIdx.x & 63;
  const int chb = (lane & 7) * 8;   // channel base (8 ch/lane)
  const int grp = lane >> 3;        // 8 edge subgroups
  if (gid != nullptr && lane == 0) {
    int g = gid[w];
    if (w == 0 || gid[w - 1] != g) gstart[g] = w;
  }
  const int start = rowptr[w] + bsum[w >> 11];
  const int cnt = deg[w];
  float4 a00 = make_float4(0.f, 0.f, 0.f, 0.f);
  float4 a01 = make_float4(0.f, 0.f, 0.f, 0.f);
  float4 a10 = make_float4(0.f, 0.f, 0.f, 0.f);
  float4 a11 = make_float4(0.f, 0.f, 0.f, 0.f);
  int i = grp;
  if (nsrc != nullptr) {
    for (; i + 8 < cnt; i += 16) {
      int s0 = csr[start + i];
      int s1 = csr[start + i + 8];
      float n0 = nsrc[s0], n1 = nsrc[s1];
      const float* r0 = m + (size_t)s0 * 64 + chb;
      const float* r1 = m + (size_t)s1 * 64 + chb;
      const float4 v00 = *(const float4*)r0;
      const float4 v01 = *(const float4*)(r0 + 4);
      const float4 v10 = *(const float4*)r1;
      const float4 v11 = *(const float4*)(r1 + 4);
      a00.x = fmaf(v00.x, n0, a00.x); a00.y = fmaf(v00.y, n0, a00.y);
      a00.z = fmaf(v00.z, n0, a00.z); a00.w = fmaf(v00.w, n0, a00.w);
      a01.x = fmaf(v01.x, n0, a01.x); a01.y = fmaf(v01.y, n0, a01.y);
      a01.z = fmaf(v01.z, n0, a01.z); a01.w = fmaf(v01.w, n0, a01.w);
      a10.x = fmaf(v10.x, n1, a10.x); a10.y = fmaf(v10.y, n1, a10.y);
      a10.z = fmaf(v10.z, n1, a10.z); a10.w = fmaf(v10.w, n1, a10.w);
      a11.x = fmaf(v11.x, n1, a11.x); a11.y = fmaf(v11.y, n1, a11.y);
      a11.z = fmaf(v11.z, n1, a11.z); a11.w = fmaf(v11.w, n1, a11.w);
    }
    if (i < cnt) {
      int s0 = csr[start + i];
      float n0 = nsrc[s0];
      const float* r0 = m + (size_t)s0 * 64 + chb;
      const float4 v00 = *(const float4*)r0;
      const float4 v01 = *(const float4*)(r0 + 4);
      a00.x = fmaf(v00.x, n0, a00.x); a00.y = fmaf(v00.y, n0, a00.y);
      a00.z = fmaf(v00.z, n0, a00.z); a00.w = fmaf(v00.w, n0, a00.w);
      a01.x = fmaf(v01.x, n0, a01.x); a01.y = fmaf(v01.y, n0, a01.y);
      a01.z = fmaf(v01.z, n0, a01.z); a01.w = fmaf(v01.w, n0, a01.w);
    }
  } else {
    for (; i + 8 < cnt; i += 16) {
      int s0 = csr[start + i];
      int s1 = csr[start + i + 8];
      const float* r0 = m + (size_t)s0 * 64 + chb;
      const float* r1 = m + (size_t)s1 * 64 + chb;
      const float4 v00 = *(const float4*)r0;
      const float4 v01 = *(const float4*)(r0 + 4);
      const float4 v10 = *(const float4*)r1;
      const float4 v11 = *(const float4*)(r1 + 4);
      a00.x += v00.x; a00.y += v00.y; a00.z += v00.z; a00.w += v00.w;
      a01.x += v01.x; a01.y += v01.y; a01.z += v01.z; a01.w += v01.w;
      a10.x += v10.x; a10.y += v10.y; a10.z += v10.z; a10.w += v10.w;
      a11.x += v11.x; a11.y += v11.y; a11.z += v11.z; a11.w += v11.w;
    }
    if (i < cnt) {
      int s0 = csr[start + i];
      const float* r0 = m + (size_t)s0 * 64 + chb;
      const float4 v00 = *(const float4*)r0;
      const float4 v01 = *(const float4*)(r0 + 4);
      a00.x += v00.x; a00.y += v00.y; a00.z += v00.z; a00.w += v00.w;
      a01.x += v01.x; a01.y += v01.y; a01.z += v01.z; a01.w += v01.w;
    }
  }
  a00.x += a10.x; a00.y += a10.y; a00.z += a10.z; a00.w += a10.w;
  a01.x += a11.x; a01.y += a11.y; a01.z += a11.z; a01.w += a11.w;
#pragma unroll
  for (int off = 8; off <= 32; off <<= 1) {
    a00.x += __shfl_xor(a00.x, off, 64);
    a00.y += __shfl_xor(a00.y, off, 64);
    a00.z += __shfl_xor(a00.z, off, 64);
    a00.w += __shfl_xor(a00.w, off, 64);
    a01.x += __shfl_xor(a01.x, off, 64);
    a01.y += __shfl_xor(a01.y, off, 64);
    a01.z += __shfl_xor(a01.z, off, 64);
    a01.w += __shfl_xor(a01.w, off, 64);
  }
  const float nd = norm_d[w];
  const float4 b0 = *(const float4*)(bias + chb);
  const float4 b1 = *(const float4*)(bias + chb + 4);
  float4 o0, o1;
  o0.x = fmaxf(fmaf(a00.x, nd, b0.x), 0.f);
  o0.y = fmaxf(fmaf(a00.y, nd, b0.y), 0.f);
  o0.z = fmaxf(fmaf(a00.z, nd, b0.z), 0.f);
  o0.w = fmaxf(fmaf(a00.w, nd, b0.w), 0.f);
  o1.x = fmaxf(fmaf(a01.x, nd, b1.x), 0.f);
  o1.y = fmaxf(fmaf(a01.y, nd, b1.y), 0.f);
  o1.z = fmaxf(fmaf(a01.z, nd, b1.z), 0.f);
  o1.w = fmaxf(fmaf(a01.w, nd, b1.w), 0.f);
  if (grp == 0) {
    *(float4*)(h + (size_t)w * 64 + chb)     = o0;
    *(float4*)(h + (size_t)w * 64 + chb + 4) = o1;
  }
  if (key != nullptr) {
    float mx = fmaxf(fmaxf(fmaxf(o0.x, o0.y), fmaxf(o0.z, o0.w)),
                     fmaxf(fmaxf(o1.x, o1.y), fmaxf(o1.z, o1.w)));
#pragma unroll
    for (int off = 1; off < 8; off <<= 1) mx = fmaxf(mx, __shfl_xor(mx, off, 64));
    if (lane == 0) key[w] = mx;
  }
}

// ---------------- fused tail: top3 + bitonic sort-pool + classifier + gcnt
__global__ void __launch_bounds__(256) k_tail(
    const float* __restrict__ key, const int* __restrict__ gstart,
    const float* __restrict__ h,
    const float* __restrict__ cw, const float* __restrict__ cb,
    const float* __restrict__ Wc, const float* __restrict__ bc,
    float* __restrict__ out, int B, int N) {
  __shared__ int sel[3];
  __shared__ float prow[192];
  const int b = blockIdx.x;
  const int wid = threadIdx.x >> 6;
  const int lane = threadIdx.x & 63;

  if (wid == 0) {
    // fused gcnt: next non-empty graph's start (sorted gid => increasing)
    const int gs = gstart[b];
    int g2 = b + 1;
    while (g2 < B && gstart[g2] >= N) ++g2;   // skip empty graphs (sentinel)
    const int ns = (g2 < B) ? gstart[g2] : N;
    const int s = gs;
    const int c = (gs < N) ? (ns - gs) : 0;
    float v0 = -1.f, v1 = -1.f, v2 = -1.f;
    int i0 = 0x7fffffff, i1 = 0x7fffffff, i2 = 0x7fffffff;
    for (int i = s + lane; i < s + c; i += 64) {
      float kv = key[i];
      if (kv > v0 || (kv == v0 && i < i0)) {
        v2 = v1; i2 = i1; v1 = v0; i1 = i0; v0 = kv; i0 = i;
      } else if (kv > v1 || (kv == v1 && i < i1)) {
        v2 = v1; i2 = i1; v1 = kv; i1 = i;
      } else if (kv > v2 || (kv == v2 && i < i2)) {
        v2 = kv; i2 = i;
      }
    }
    int ptr = 0;
    for (int r = 0; r < 3; ++r) {
      float mv = (ptr == 0) ? v0 : (ptr == 1) ? v1 : (ptr == 2) ? v2 : -1.f;
      int   mi = (ptr == 0) ? i0 : (ptr == 1) ? i1 : (ptr == 2) ? i2 : 0x7fffffff;
      float bv = mv; int bi = mi;
#pragma unroll
      for (int off = 32; off; off >>= 1) {
        float ov = __shfl_xor(bv, off, 64);
        int   oi = __shfl_xor(bi, off, 64);
        if (ov > bv || (ov == bv && oi < bi)) { bv = ov; bi = oi; }
      }
      if (bi == mi && ptr < 3) ptr++;             // winner's owner pops
      if (lane == 0) sel[r] = (bi == 0x7fffffff) ? -1 : bi;
    }
  }
  __syncthreads();
  if (wid < 3) {
    int node = sel[wid];
    float v = 0.f;
    if (node >= 0) {
      v = h[(size_t)node * 64 + lane];
      for (int k2 = 2; k2 <= 64; k2 <<= 1) {
        for (int j = k2 >> 1; j > 0; j >>= 1) {
          float o = __shfl_xor(v, j, 64);
          bool up = ((lane & k2) == 0);
          bool lower = ((lane & j) == 0);
          v = (lower == up) ? fminf(v, o) : fmaxf(v, o);
        }
      }
    }
    prow[wid * 64 + lane] = v;
  }
  __syncthreads();
  if (wid == 0) {
    float y = cb[lane];
    for (int j = 0; j < 192; ++j) y = fmaf(prow[j], cw[lane * 192 + j], y);
    float ry = fmaxf(y, 0.f);
    for (int c = 0; c < 10; ++c) {
      float s = ry * Wc[lane * 10 + c];
#pragma unroll
      for (int off = 32; off; off >>= 1) s += __shfl_xor(s, off, 64);
      if (lane == 0) out[b * 10 + c] = s + bc[c];
    }
  }
}

// ================================================================ launch
extern "C" void kernel_launch(void* const* d_in, const int* in_sizes, int n_in,
                              void* d_out, int out_size, void* d_ws, size_t ws_size,
                              hipStream_t stream) {
  const float* features = (const float*)d_in[0];
  const int*   esrc     = (const int*)d_in[1];
  const int*   edst     = (const int*)d_in[2];
  const int*   gid      = (const int*)d_in[3];
  const float* W1 = (const float*)d_in[5];
  const float* b1 = (const float*)d_in[6];
  const float* W2 = (const float*)d_in[7];
  const float* b2 = (const float*)d_in[8];
  const float* cw = (const float*)d_in[9];
  const float* cb = (const float*)d_in[10];
  const float* Wc = (const float*)d_in[11];
  const float* bc = (const float*)d_in[12];
  float* out = (float*)d_out;

  const int N = in_sizes[0] / 64;
  const int E = in_sizes[1];
  const int B = out_size / 10;
  const size_t N64 = (size_t)N * 64;
  const int nscan = (N + 2047) / 2048;          // <= 64 for N <= 131072
  const int PH = (N + PART_H - 1) / PART_H;     // 2 for N=100k
  const int PF = (N + PART_F - 1) / PART_F;     // 4 for N=100k
  const size_t HSZ = (size_t)PH * MCH * PART_H; // u8 hist bytes (~6.4 MB)
  const int NT = (N + 127) / 128;               // gemm tiles
  const int histBlocks = 2 * PH * MCH;          // 256

  // workspace carve-up (~75 MB of the 256 MB ws; fully disjoint).
  float* bufA   = (float*)d_ws;            // N*64 : m1 -> m2
  float* bufB   = bufA + N64;              // N*64 : h1 -> h2
  int*   deg_d  = (int*)(bufB + N64);      // N
  float* norm_s = (float*)(deg_d + N);     // N
  float* norm_d = norm_s + N;              // N
  float* key    = norm_d + N;              // N
  int*   rowptr = (int*)(key + N);         // N
  int*   csr    = rowptr + N;              // E
  int*   bsum   = csr + E;                 // <=64
  int*   gstart = bsum + 64;               // B
  unsigned char* hd = (unsigned char*)(gstart + B);  // HSZ u8
  unsigned char* hs = hd + HSZ;                      // HSZ u8

  const int TB = 256;

  // ---- CSR build overlapped with gemm1 (un-normed; norm_s applied in gather1)
  k_histgemm<<<histBlocks + NT, TB, 0, stream>>>(esrc, edst, hd, hs,
                                                 features, W1, bufA,
                                                 N, E, PH, histBlocks);
  k_off<<<(N + TB - 1) / TB, TB, 0, stream>>>(hd, hs, deg_d, norm_s, norm_d,
                                              gstart, B, N);
  k_scan1<<<nscan, 256, 0, stream>>>(deg_d, rowptr, bsum, N);
  k_scan2<<<1, 64, 0, stream>>>(bsum, nscan);
  k_fill2<<<PF * MCH, TB, 0, stream>>>(esrc, edst, hd, rowptr, bsum, csr, N, E, PF);

  // ---- layer 1 gather (applies norm_s per source)
  k_gather<<<(N + 3) / 4, TB, 0, stream>>>(bufA, rowptr, bsum, deg_d, norm_d, b1,
                                           csr, norm_s, nullptr, nullptr,
                                           bufB, nullptr, N);

  // ---- layer 2
  k_gemm64<<<NT, TB, 0, stream>>>(bufB, norm_s, W2, bufA, N);
  k_gather<<<(N + 3) / 4, TB, 0, stream>>>(bufA, rowptr, bsum, deg_d, norm_d, b2,
                                           csr, nullptr, gid, gstart,
                                           bufB, key, N);

  // ---- pooling + classifier (gcnt fused into tail)
  k_tail<<<B, TB, 0, stream>>>(key, gstart, bufB, cw, cb, Wc, bc, out, B, N);
}